// Round 1
// baseline (1965.881 us; speedup 1.0000x reference)
//
#include <hip/hip_runtime.h>
#include <hip/hip_bf16.h>
#include <cstdint>
#include <cstddef>

// Problem constants
#define N_NODE 100000
#define N_EDGE 1600000
#define N_REL  4
#define DIM    128
#define KDIM   512                               // N_REL * DIM stacked
#define HALF_N 50000
#define CHUNK  2048
#define NCH    ((N_NODE + CHUNK - 1) / CHUNK)   // 49

typedef __attribute__((ext_vector_type(8))) short bf16x8;   // 8 bf16 (4 VGPRs)
typedef __attribute__((ext_vector_type(4))) float f32x4;    // 4 fp32 acc

__device__ inline unsigned short f2bf(float f) {
    __hip_bfloat16 b = __float2bfloat16(f);
    return *reinterpret_cast<unsigned short*>(&b);
}

// ---------------------------------------------------------------------------
// 0) Zero the two degree-count tables (workspace persists across launches).
// ---------------------------------------------------------------------------
__global__ void k_zero2(int4* __restrict__ a, int4* __restrict__ b) {
    int i = blockIdx.x * 256 + threadIdx.x;
    if (i < (N_REL * N_NODE) / 4) {
        a[i] = make_int4(0, 0, 0, 0);
        b[i] = make_int4(0, 0, 0, 0);
    }
}

// ---------------------------------------------------------------------------
// 1) Single-pass degree count via global atomics (L2-resident 1.6MB tables).
//    Replaces the 4-pass tiled LDS histograms + partial-table reduce.
// ---------------------------------------------------------------------------
__global__ __launch_bounds__(256) void k_count(const int* __restrict__ src,
                                               const int* __restrict__ dst,
                                               int* __restrict__ cnt_out,
                                               int* __restrict__ cnt_in) {
    int r = blockIdx.y;
    int q = blockIdx.x * 256 + threadIdx.x;      // 8 edges per thread
    if (q * 8 >= N_EDGE) return;
    size_t roff = (size_t)r * N_EDGE;
    const int4* dp = (const int4*)(dst + roff);
    const int4* sp = (const int4*)(src + roff);
    int4 d4a = dp[2 * q], d4b = dp[2 * q + 1];
    int4 s4a = sp[2 * q], s4b = sp[2 * q + 1];
    int* ci = cnt_in  + r * N_NODE;
    int* co = cnt_out + r * N_NODE;
    atomicAdd(&ci[d4a.x], 1); atomicAdd(&ci[d4a.y], 1);
    atomicAdd(&ci[d4a.z], 1); atomicAdd(&ci[d4a.w], 1);
    atomicAdd(&ci[d4b.x], 1); atomicAdd(&ci[d4b.y], 1);
    atomicAdd(&ci[d4b.z], 1); atomicAdd(&ci[d4b.w], 1);
    atomicAdd(&co[s4a.x], 1); atomicAdd(&co[s4a.y], 1);
    atomicAdd(&co[s4a.z], 1); atomicAdd(&co[s4a.w], 1);
    atomicAdd(&co[s4b.x], 1); atomicAdd(&co[s4b.y], 1);
    atomicAdd(&co[s4b.z], 1); atomicAdd(&co[s4b.w], 1);
}

// 2) rinv from degree counts (clamped >= 1 per DGL norm='both').
__global__ void k_rinv(const int* __restrict__ cnt_in, const int* __restrict__ cnt_out,
                       float* __restrict__ rinv_in, float* __restrict__ rinv_out) {
    int i = blockIdx.x * blockDim.x + threadIdx.x;
    if (i >= N_REL * N_NODE) return;
    rinv_in[i]  = rsqrtf((float)max(cnt_in[i], 1));
    rinv_out[i] = rsqrtf((float)max(cnt_out[i], 1));
}

// ---------------------------------------------------------------------------
// 3) CSR-by-dst row_ptr: chunk sums -> scan partials -> chunk scan (+cursors)
// ---------------------------------------------------------------------------
__global__ void k_chunk_sum(const int* __restrict__ cnt_in, int* __restrict__ partials) {
    int r = blockIdx.y, ch = blockIdx.x;
    __shared__ int sdata[256];
    int s = 0;
    for (int i = 0; i < CHUNK / 256; ++i) {
        int n = ch * CHUNK + i * 256 + threadIdx.x;
        if (n < N_NODE) s += cnt_in[r * N_NODE + n];
    }
    sdata[threadIdx.x] = s;
    __syncthreads();
    for (int off = 128; off > 0; off >>= 1) {
        if (threadIdx.x < off) sdata[threadIdx.x] += sdata[threadIdx.x + off];
        __syncthreads();
    }
    if (threadIdx.x == 0) partials[r * NCH + ch] = sdata[0];
}

__global__ void k_scan_partials(const int* __restrict__ partials,
                                int* __restrict__ chunk_base, int* __restrict__ row_ptr) {
    __shared__ int sp[N_REL * NCH];
    int t = threadIdx.x;
    if (t < N_REL * NCH) sp[t] = partials[t];
    __syncthreads();
    if (t == 0) {
        for (int r = 0; r < N_REL; ++r) {
            int run = 0;
            for (int ch = 0; ch < NCH; ++ch) {
                chunk_base[r * NCH + ch] = run;
                run += sp[r * NCH + ch];
            }
            row_ptr[r * (N_NODE + 1) + N_NODE] = N_EDGE;
        }
    }
}

__global__ void k_chunk_scan(const int* __restrict__ cnt_in,
                             const int* __restrict__ chunk_base,
                             int* __restrict__ row_ptr, int* __restrict__ cur) {
    int r = blockIdx.y, ch = blockIdx.x;
    __shared__ int tsum[256];
    int base_n = ch * CHUNK;
    int vals[8];
    int loc = 0;
    for (int i = 0; i < 8; ++i) {
        int n = base_n + threadIdx.x * 8 + i;
        vals[i] = (n < N_NODE) ? cnt_in[r * N_NODE + n] : 0;
        loc += vals[i];
    }
    tsum[threadIdx.x] = loc;
    __syncthreads();
    for (int off = 1; off < 256; off <<= 1) {     // Hillis-Steele inclusive scan
        int y = (threadIdx.x >= off) ? tsum[threadIdx.x - off] : 0;
        __syncthreads();
        tsum[threadIdx.x] += y;
        __syncthreads();
    }
    int pos = chunk_base[r * NCH + ch] + tsum[threadIdx.x] - loc;  // exclusive
    for (int i = 0; i < 8; ++i) {
        int n = base_n + threadIdx.x * 8 + i;
        if (n < N_NODE) {
            row_ptr[r * (N_NODE + 1) + n] = pos;
            cur[r * N_NODE + n] = pos;              // scatter cursors init
            pos += vals[i];
        }
    }
}

// ---------------------------------------------------------------------------
// 4) Single-pass scatter with global atomic cursors. Edges read ONCE (was 4x);
//    per-hit chain is atomic(ret) -> store, 8 edges in flight per thread, no
//    LDS -> no occupancy cap. rinv_out folded in as before.
// ---------------------------------------------------------------------------
__global__ __launch_bounds__(256) void k_scatter_g(const int* __restrict__ src,
                          const int* __restrict__ dst, const float* __restrict__ ew,
                          int* __restrict__ cur, const float* __restrict__ rinv_out,
                          int2* __restrict__ pk_s) {
    int r = blockIdx.y;
    int q = blockIdx.x * 256 + threadIdx.x;      // 8 edges per thread
    if (q * 8 >= N_EDGE) return;
    size_t roff = (size_t)r * N_EDGE;
    const int4*   dp = (const int4*)  (dst + roff);
    const int4*   sp = (const int4*)  (src + roff);
    const float4* wp = (const float4*)(ew  + roff);
    int4   d4a = dp[2 * q], d4b = dp[2 * q + 1];
    int4   s4a = sp[2 * q], s4b = sp[2 * q + 1];
    float4 w4a = wp[2 * q], w4b = wp[2 * q + 1];
    int* cu = cur + r * N_NODE;
    const float* ro = rinv_out + (size_t)r * N_NODE;

    int   d[8] = {d4a.x, d4a.y, d4a.z, d4a.w, d4b.x, d4b.y, d4b.z, d4b.w};
    int   s[8] = {s4a.x, s4a.y, s4a.z, s4a.w, s4b.x, s4b.y, s4b.z, s4b.w};
    float w[8] = {w4a.x, w4a.y, w4a.z, w4a.w, w4b.x, w4b.y, w4b.z, w4b.w};
    int   k[8];
    float c[8];
#pragma unroll
    for (int i = 0; i < 8; ++i) k[i] = atomicAdd(&cu[d[i]], 1);   // independent
#pragma unroll
    for (int i = 0; i < 8; ++i) c[i] = w[i] * ro[s[i]];           // independent
#pragma unroll
    for (int i = 0; i < 8; ++i)
        pk_s[roff + k[i]] = make_int2(s[i], __float_as_int(c[i]));
}

// 7a) fp32 -> bf16 matrix convert (4 elems/thread)
__global__ void k_cvt(const float* __restrict__ x, unsigned short* __restrict__ xb) {
    int i = blockIdx.x * blockDim.x + threadIdx.x;
    if (i >= N_NODE * DIM / 4) return;
    float4 v = ((const float4*)x)[i];
    ushort4 o;
    o.x = f2bf(v.x); o.y = f2bf(v.y); o.z = f2bf(v.z); o.w = f2bf(v.w);
    ((ushort4*)xb)[i] = o;
}

// 7b) W [512][128] fp32 -> WT [128][512] bf16 (transpose for B-frag loads)
__global__ void k_cvt_w(const float* __restrict__ W, unsigned short* __restrict__ WT) {
    int i = blockIdx.x * blockDim.x + threadIdx.x;
    if (i >= KDIM * DIM) return;
    int k = i >> 7, j = i & 127;
    WT[(size_t)j * KDIM + k] = f2bf(W[i]);
}

// ---------------------------------------------------------------------------
// 8) Fused SpMM: one wave per (node, relation); 8-deep gather pipeline.
//    Block = 1 node x 4 relation-waves; lane owns dword `lane` of 256B row.
// ---------------------------------------------------------------------------
__global__ __launch_bounds__(256) void k_spmm4(const int* __restrict__ row_ptr,
                        const int2* __restrict__ pk_s,
                        const float* __restrict__ rinv_in, const unsigned* __restrict__ hb,
                        unsigned* __restrict__ Tb, int node0) {
    int r    = threadIdx.x >> 6;          // wave index = relation
    int lane = threadIdx.x & 63;
    int nl   = blockIdx.x;                // local row within half
    int node = node0 + nl;
    int k0 = row_ptr[r * (N_NODE + 1) + node];
    int k1 = row_ptr[r * (N_NODE + 1) + node + 1];
    const int2* pp = pk_s + (size_t)r * N_EDGE;
    float2 acc = make_float2(0.f, 0.f);
    int k = k0;
    for (; k + 7 < k1; k += 8) {
        int2 p0 = pp[k],     p1 = pp[k + 1], p2 = pp[k + 2], p3 = pp[k + 3];
        int2 p4 = pp[k + 4], p5 = pp[k + 5], p6 = pp[k + 6], p7 = pp[k + 7];
        unsigned u0 = hb[(size_t)p0.x * 64 + lane];
        unsigned u1 = hb[(size_t)p1.x * 64 + lane];
        unsigned u2 = hb[(size_t)p2.x * 64 + lane];
        unsigned u3 = hb[(size_t)p3.x * 64 + lane];
        unsigned u4 = hb[(size_t)p4.x * 64 + lane];
        unsigned u5 = hb[(size_t)p5.x * 64 + lane];
        unsigned u6 = hb[(size_t)p6.x * 64 + lane];
        unsigned u7 = hb[(size_t)p7.x * 64 + lane];
        float c0 = __int_as_float(p0.y), c1 = __int_as_float(p1.y);
        float c2 = __int_as_float(p2.y), c3 = __int_as_float(p3.y);
        float c4 = __int_as_float(p4.y), c5 = __int_as_float(p5.y);
        float c6 = __int_as_float(p6.y), c7 = __int_as_float(p7.y);
        acc.x += c0 * __uint_as_float(u0 << 16);
        acc.y += c0 * __uint_as_float(u0 & 0xffff0000u);
        acc.x += c1 * __uint_as_float(u1 << 16);
        acc.y += c1 * __uint_as_float(u1 & 0xffff0000u);
        acc.x += c2 * __uint_as_float(u2 << 16);
        acc.y += c2 * __uint_as_float(u2 & 0xffff0000u);
        acc.x += c3 * __uint_as_float(u3 << 16);
        acc.y += c3 * __uint_as_float(u3 & 0xffff0000u);
        acc.x += c4 * __uint_as_float(u4 << 16);
        acc.y += c4 * __uint_as_float(u4 & 0xffff0000u);
        acc.x += c5 * __uint_as_float(u5 << 16);
        acc.y += c5 * __uint_as_float(u5 & 0xffff0000u);
        acc.x += c6 * __uint_as_float(u6 << 16);
        acc.y += c6 * __uint_as_float(u6 & 0xffff0000u);
        acc.x += c7 * __uint_as_float(u7 << 16);
        acc.y += c7 * __uint_as_float(u7 & 0xffff0000u);
    }
    for (; k < k1; ++k) {
        int2 p0 = pp[k];
        unsigned u0 = hb[(size_t)p0.x * 64 + lane];
        float c0 = __int_as_float(p0.y);
        acc.x += c0 * __uint_as_float(u0 << 16);
        acc.y += c0 * __uint_as_float(u0 & 0xffff0000u);
    }
    float ri = rinv_in[r * N_NODE + node];
    acc.x *= ri; acc.y *= ri;
    Tb[(size_t)nl * 256 + r * 64 + lane] =
        ((unsigned)f2bf(acc.y) << 16) | (unsigned)f2bf(acc.x);
}

// ---------------------------------------------------------------------------
// 9) MFMA GEMM: out[HALF_N,128] = relu(T[HALF_N,512] @ Wcat[512,128] + bias_sum)
//    mfma_f32_16x16x32_bf16; verified frag layouts (A: m=lane&15,k=(lane>>4)*8+j;
//    C/D: col=lane&15, row=(lane>>4)*4+reg). WT (128KB) L2-resident, no LDS.
// ---------------------------------------------------------------------------
__global__ __launch_bounds__(256) void k_gemm(const unsigned short* __restrict__ Tb,
                                              const unsigned short* __restrict__ WT,
                                              const float* __restrict__ b,
                                              float* __restrict__ outf,
                                              unsigned short* __restrict__ outb,
                                              int node0) {
    int lane = threadIdx.x & 63;
    int wv   = threadIdx.x >> 6;
    int row0 = blockIdx.x * 64 + wv * 16;
    if (row0 >= HALF_N) return;            // HALF_N % 16 == 0: full-or-empty
    int m  = lane & 15;
    int kg = lane >> 4;

    f32x4 acc[8];
#pragma unroll
    for (int t = 0; t < 8; ++t) acc[t] = (f32x4){0.f, 0.f, 0.f, 0.f};

    const unsigned short* arow = Tb + (size_t)(row0 + m) * KDIM + kg * 8;
    for (int k0 = 0; k0 < KDIM; k0 += 32) {
        bf16x8 af = *(const bf16x8*)(arow + k0);
#pragma unroll
        for (int t = 0; t < 8; ++t) {
            bf16x8 bf = *(const bf16x8*)(WT + (size_t)(t * 16 + m) * KDIM + k0 + kg * 8);
            acc[t] = __builtin_amdgcn_mfma_f32_16x16x32_bf16(af, bf, acc[t], 0, 0, 0);
        }
    }

    int rbase = row0 + kg * 4;
#pragma unroll
    for (int t = 0; t < 8; ++t) {
        int col = t * 16 + m;
        float bs = b[col] + b[DIM + col] + b[2 * DIM + col] + b[3 * DIM + col];
#pragma unroll
        for (int rg = 0; rg < 4; ++rg) {
            float v = acc[t][rg] + bs;
            v = v > 0.f ? v : 0.f;         // relu in BOTH layers per reference
            size_t o = (size_t)(node0 + rbase + rg) * DIM + col;
            if (outb) outb[o] = f2bf(v);
            else      outf[o] = v;
        }
    }
}

// ---------------------------------------------------------------------------
extern "C" void kernel_launch(void* const* d_in, const int* in_sizes, int n_in,
                              void* d_out, int out_size, void* d_ws, size_t ws_size,
                              hipStream_t stream) {
    const float* x   = (const float*)d_in[0];
    const int*   src = (const int*)  d_in[1];
    const int*   dst = (const int*)  d_in[2];
    const float* ew  = (const float*)d_in[3];
    const float* W1  = (const float*)d_in[4];
    const float* b1  = (const float*)d_in[5];
    const float* W2  = (const float*)d_in[6];
    const float* b2  = (const float*)d_in[7];
    float* out = (float*)d_out;

    // Workspace carve-up (same proven ~160 MB footprint as before).
    char* p = (char*)d_ws;
    auto alloc = [&](size_t bytes) -> char* {
        char* q = p;
        p += (bytes + 255) & ~(size_t)255;
        return q;
    };
    const size_t RN = (size_t)N_REL * N_NODE;
    int*   cnt_in     = (int*)  alloc(RN * 4);
    float* rinv_out   = (float*)alloc(RN * 4);
    float* rinv_in    = (float*)alloc(RN * 4);
    int*   row_ptr    = (int*)  alloc((size_t)N_REL * (N_NODE + 1) * 4);
    int*   partials   = (int*)  alloc(N_REL * NCH * 4);
    int*   chunk_base = (int*)  alloc(N_REL * NCH * 4);
    unsigned short* WT1b = (unsigned short*)alloc((size_t)KDIM * DIM * 2);  // 128KB
    unsigned short* WT2b = (unsigned short*)alloc((size_t)KDIM * DIM * 2);  // 128KB
    int2*  pk_s       = (int2*) alloc((size_t)N_REL * N_EDGE * 8);          // 51.2 MB
    char*  Treg       =         alloc((size_t)HALF_N * KDIM * 2);           // 51.2 MB
    char*  hreg       =         alloc((size_t)N_NODE * DIM * 2 * 2);        // 51.2 MB

    // Aliases:
    // cur / cnt_out live in Treg (dead before first spmm writes Tb there).
    // hreg: [0, 25.6MB) h_mid_b (bf16 layer-1 out), [25.6, 51.2) xb (bf16 x).
    int* cur     = (int*)Treg;
    int* cnt_out = (int*)(Treg + RN * 4);
    unsigned short* h_mid_b = (unsigned short*)hreg;
    unsigned short* xb      = (unsigned short*)(hreg + (size_t)N_NODE * DIM * 2);
    unsigned short* Tb      = (unsigned short*)Treg;

    const int EB = (N_EDGE / 8 + 255) / 256;   // 782 blocks/relation, 8 edges/thread

    k_zero2<<<(int)(RN / 4 + 255) / 256, 256, 0, stream>>>((int4*)cnt_in, (int4*)cnt_out);
    k_count<<<dim3(EB, N_REL), 256, 0, stream>>>(src, dst, cnt_out, cnt_in);
    k_rinv<<<((int)RN + 255) / 256, 256, 0, stream>>>(cnt_in, cnt_out, rinv_in, rinv_out);
    k_cvt<<<(N_NODE * DIM / 4 + 255) / 256, 256, 0, stream>>>(x, xb);
    k_cvt_w<<<(KDIM * DIM + 255) / 256, 256, 0, stream>>>(W1, WT1b);
    k_cvt_w<<<(KDIM * DIM + 255) / 256, 256, 0, stream>>>(W2, WT2b);
    k_chunk_sum<<<dim3(NCH, N_REL), 256, 0, stream>>>(cnt_in, partials);
    k_scan_partials<<<1, 256, 0, stream>>>(partials, chunk_base, row_ptr);
    k_chunk_scan<<<dim3(NCH, N_REL), 256, 0, stream>>>(cnt_in, chunk_base, row_ptr, cur);
    k_scatter_g<<<dim3(EB, N_REL), 256, 0, stream>>>(src, dst, ew, cur, rinv_out, pk_s);

    const int spmm_grid = HALF_N;              // one node per block, 4 r-waves
    const int gemm_grid = (HALF_N + 63) / 64;  // 782

    // layer 1: xb (bf16) -> h_mid_b (bf16), two halves through Tb
    for (int h = 0; h < 2; ++h) {
        k_spmm4<<<spmm_grid, 256, 0, stream>>>(row_ptr, pk_s, rinv_in,
                                               (const unsigned*)xb, (unsigned*)Tb, h * HALF_N);
        k_gemm<<<gemm_grid, 256, 0, stream>>>(Tb, WT1b, b1, (float*)nullptr, h_mid_b, h * HALF_N);
    }
    // layer 2: h_mid_b (bf16) -> out (fp32)
    for (int h = 0; h < 2; ++h) {
        k_spmm4<<<spmm_grid, 256, 0, stream>>>(row_ptr, pk_s, rinv_in,
                                               (const unsigned*)h_mid_b, (unsigned*)Tb, h * HALF_N);
        k_gemm<<<gemm_grid, 256, 0, stream>>>(Tb, WT2b, b2, out, (unsigned short*)nullptr, h * HALF_N);
    }
}

// Round 2
// 1284.554 us; speedup vs baseline: 1.5304x; 1.5304x over previous
//
#include <hip/hip_runtime.h>
#include <hip/hip_bf16.h>
#include <cstdint>
#include <cstddef>

// Problem constants
#define N_NODE 100000
#define N_EDGE 1600000
#define N_REL  4
#define DIM    128
#define KDIM   512                               // N_REL * DIM stacked
#define HALF_N 50000
#define CHUNK  2048
#define NCH    ((N_NODE + CHUNK - 1) / CHUNK)   // 49

// Histogram/scatter tiling: packed u16 counters -> TS=25000 in 50KB LDS,
// 4 passes. 512-thread blocks, 3 blocks/CU LDS cap. (Global-atomic variant
// was tried and is 2x WORSE: cross-XCD atomic RMW = 400MB HBM write, 497us.)
#define CH_E   50000                             // edges per chunk (div by 4)
#define NCHUNK 32                                // chunks (Pd table caps this)
#define TS     25000                             // node-tile size (even)
#define NTILE  4                                 // ceil(100000/25000)

typedef __attribute__((ext_vector_type(8))) short bf16x8;   // 8 bf16 (4 VGPRs)
typedef __attribute__((ext_vector_type(4))) float f32x4;    // 4 fp32 acc

__device__ inline unsigned short f2bf(float f) {
    __hip_bfloat16 b = __float2bfloat16(f);
    return *reinterpret_cast<unsigned short*>(&b);
}

// ---------------------------------------------------------------------------
// 1) Tiled LDS histogram, packed u16 fields (count <= 50000 < 2^16).
// ---------------------------------------------------------------------------
__global__ __launch_bounds__(512) void k_hist(const int* __restrict__ idx,
                                              int* __restrict__ P) {
    __shared__ unsigned hist[TS / 2];            // 50 KB
    int c = blockIdx.x, t = blockIdx.y, r = blockIdx.z;
    for (int i = threadIdx.x; i < TS / 2; i += 512) hist[i] = 0;
    __syncthreads();
    int n0 = t * TS;
    int e0 = c * CH_E;
    const int* ip = idx + (size_t)r * N_EDGE;
    for (int e = e0 + threadIdx.x * 4; e < e0 + CH_E; e += 2048) {
        int4 d4 = *(const int4*)(ip + e);
        unsigned a0 = (unsigned)(d4.x - n0), a1 = (unsigned)(d4.y - n0);
        unsigned a2 = (unsigned)(d4.z - n0), a3 = (unsigned)(d4.w - n0);
        if (a0 < TS) atomicAdd(&hist[a0 >> 1], 1u << (16 * (a0 & 1)));
        if (a1 < TS) atomicAdd(&hist[a1 >> 1], 1u << (16 * (a1 & 1)));
        if (a2 < TS) atomicAdd(&hist[a2 >> 1], 1u << (16 * (a2 & 1)));
        if (a3 < TS) atomicAdd(&hist[a3 >> 1], 1u << (16 * (a3 & 1)));
    }
    __syncthreads();
    int* Pp = P + ((size_t)r * NCHUNK + c) * N_NODE;
    for (int i = threadIdx.x; i < TS; i += 512) {
        int n = n0 + i;
        if (n < N_NODE)
            Pp[n] = (int)((hist[i >> 1] >> (16 * (i & 1))) & 0xffffu);
    }
}

// 2) Reduce partials over chunks -> cnt_in (for scan) + rinv_in/out
__global__ void k_reduce_rinv(const int* __restrict__ Pd, const int* __restrict__ Ps,
                              int* __restrict__ cnt_in, float* __restrict__ rinv_in,
                              float* __restrict__ rinv_out) {
    int i = blockIdx.x * blockDim.x + threadIdx.x;   // r*N + n
    if (i >= N_REL * N_NODE) return;
    int r = i / N_NODE, n = i - r * N_NODE;
    int ci = 0, co = 0;
#pragma unroll
    for (int c = 0; c < NCHUNK; ++c) {
        ci += Pd[((size_t)r * NCHUNK + c) * N_NODE + n];
        co += Ps[((size_t)r * NCHUNK + c) * N_NODE + n];
    }
    cnt_in[i]   = ci;
    rinv_in[i]  = rsqrtf((float)max(ci, 1));
    rinv_out[i] = rsqrtf((float)max(co, 1));
}

// ---------------------------------------------------------------------------
// 3) CSR-by-dst row_ptr: chunk sums -> scan partials -> chunk scan
// ---------------------------------------------------------------------------
__global__ void k_chunk_sum(const int* __restrict__ cnt_in, int* __restrict__ partials) {
    int r = blockIdx.y, ch = blockIdx.x;
    __shared__ int sdata[256];
    int s = 0;
    for (int i = 0; i < CHUNK / 256; ++i) {
        int n = ch * CHUNK + i * 256 + threadIdx.x;
        if (n < N_NODE) s += cnt_in[r * N_NODE + n];
    }
    sdata[threadIdx.x] = s;
    __syncthreads();
    for (int off = 128; off > 0; off >>= 1) {
        if (threadIdx.x < off) sdata[threadIdx.x] += sdata[threadIdx.x + off];
        __syncthreads();
    }
    if (threadIdx.x == 0) partials[r * NCH + ch] = sdata[0];
}

__global__ void k_scan_partials(const int* __restrict__ partials,
                                int* __restrict__ chunk_base, int* __restrict__ row_ptr) {
    __shared__ int sp[N_REL * NCH];
    int t = threadIdx.x;
    if (t < N_REL * NCH) sp[t] = partials[t];
    __syncthreads();
    if (t == 0) {
        for (int r = 0; r < N_REL; ++r) {
            int run = 0;
            for (int ch = 0; ch < NCH; ++ch) {
                chunk_base[r * NCH + ch] = run;
                run += sp[r * NCH + ch];
            }
            row_ptr[r * (N_NODE + 1) + N_NODE] = N_EDGE;
        }
    }
}

__global__ void k_chunk_scan(const int* __restrict__ cnt_in,
                             const int* __restrict__ chunk_base, int* __restrict__ row_ptr) {
    int r = blockIdx.y, ch = blockIdx.x;
    __shared__ int tsum[256];
    int base_n = ch * CHUNK;
    int vals[8];
    int loc = 0;
    for (int i = 0; i < 8; ++i) {
        int n = base_n + threadIdx.x * 8 + i;
        vals[i] = (n < N_NODE) ? cnt_in[r * N_NODE + n] : 0;
        loc += vals[i];
    }
    tsum[threadIdx.x] = loc;
    __syncthreads();
    for (int off = 1; off < 256; off <<= 1) {     // Hillis-Steele inclusive scan
        int y = (threadIdx.x >= off) ? tsum[threadIdx.x - off] : 0;
        __syncthreads();
        tsum[threadIdx.x] += y;
        __syncthreads();
    }
    int pos = chunk_base[r * NCH + ch] + tsum[threadIdx.x] - loc;  // exclusive
    for (int i = 0; i < 8; ++i) {
        int n = base_n + threadIdx.x * 8 + i;
        if (n < N_NODE) { row_ptr[r * (N_NODE + 1) + n] = pos; pos += vals[i]; }
    }
}

// 4) In-place: P[r][c][n] := row_ptr[r][n] + sum_{c'<c} P[r][c'][n]
__global__ void k_base(int* __restrict__ P, const int* __restrict__ row_ptr) {
    int i = blockIdx.x * blockDim.x + threadIdx.x;
    if (i >= N_REL * N_NODE) return;
    int r = i / N_NODE, n = i - r * N_NODE;
    int run = row_ptr[r * (N_NODE + 1) + n];
#pragma unroll
    for (int c = 0; c < NCHUNK; ++c) {
        size_t o = ((size_t)r * NCHUNK + c) * N_NODE + n;
        int p = P[o];
        P[o] = run;
        run += p;
    }
}

// 5) Scatter: packed u16 LOCAL cursors (init 0), CSR base added per-hit via
//    L2-resident 64KB-window gather; rinv_out folded in.
__global__ __launch_bounds__(512) void k_scatter5(const int* __restrict__ src,
                          const int* __restrict__ dst, const float* __restrict__ ew,
                          const int* __restrict__ base, const float* __restrict__ rinv_out,
                          int2* __restrict__ pk_s) {
    __shared__ unsigned cur[TS / 2];             // 50 KB, local ranks
    int c = blockIdx.x, t = blockIdx.y, r = blockIdx.z;
    for (int i = threadIdx.x; i < TS / 2; i += 512) cur[i] = 0;
    __syncthreads();
    int n0 = t * TS;
    int e0 = c * CH_E;
    const int*   bp = base + ((size_t)r * NCHUNK + c) * N_NODE + n0;
    const float* ro = rinv_out + (size_t)r * N_NODE;
    size_t roff = (size_t)r * N_EDGE;
    for (int e = e0 + threadIdx.x * 4; e < e0 + CH_E; e += 2048) {
        int4   d4 = *(const int4*)  (dst + roff + e);
        int4   s4 = *(const int4*)  (src + roff + e);
        float4 w4 = *(const float4*)(ew  + roff + e);
        unsigned a; unsigned old; int rank;
        a = (unsigned)(d4.x - n0);
        if (a < TS) {
            old = atomicAdd(&cur[a >> 1], 1u << (16 * (a & 1)));
            rank = (int)((old >> (16 * (a & 1))) & 0xffffu);
            pk_s[roff + bp[a] + rank] = make_int2(s4.x, __float_as_int(w4.x * ro[s4.x]));
        }
        a = (unsigned)(d4.y - n0);
        if (a < TS) {
            old = atomicAdd(&cur[a >> 1], 1u << (16 * (a & 1)));
            rank = (int)((old >> (16 * (a & 1))) & 0xffffu);
            pk_s[roff + bp[a] + rank] = make_int2(s4.y, __float_as_int(w4.y * ro[s4.y]));
        }
        a = (unsigned)(d4.z - n0);
        if (a < TS) {
            old = atomicAdd(&cur[a >> 1], 1u << (16 * (a & 1)));
            rank = (int)((old >> (16 * (a & 1))) & 0xffffu);
            pk_s[roff + bp[a] + rank] = make_int2(s4.z, __float_as_int(w4.z * ro[s4.z]));
        }
        a = (unsigned)(d4.w - n0);
        if (a < TS) {
            old = atomicAdd(&cur[a >> 1], 1u << (16 * (a & 1)));
            rank = (int)((old >> (16 * (a & 1))) & 0xffffu);
            pk_s[roff + bp[a] + rank] = make_int2(s4.w, __float_as_int(w4.w * ro[s4.w]));
        }
    }
}

// 7a) fp32 -> bf16 matrix convert (4 elems/thread)
__global__ void k_cvt(const float* __restrict__ x, unsigned short* __restrict__ xb) {
    int i = blockIdx.x * blockDim.x + threadIdx.x;
    if (i >= N_NODE * DIM / 4) return;
    float4 v = ((const float4*)x)[i];
    ushort4 o;
    o.x = f2bf(v.x); o.y = f2bf(v.y); o.z = f2bf(v.z); o.w = f2bf(v.w);
    ((ushort4*)xb)[i] = o;
}

// 7b) W [512][128] fp32 -> WT [128][512] bf16 (transpose for B-frag loads)
__global__ void k_cvt_w(const float* __restrict__ W, unsigned short* __restrict__ WT) {
    int i = blockIdx.x * blockDim.x + threadIdx.x;
    if (i >= KDIM * DIM) return;
    int k = i >> 7, j = i & 127;
    WT[(size_t)j * KDIM + k] = f2bf(W[i]);
}

// ---------------------------------------------------------------------------
// 8) Fused SpMM, wide-gather version: lane owns a 16B (dwordx4) slice of the
//    256B feature row; 16 lanes/row => 4 edges in flight per wave per step,
//    4-deep unroll = 16 edges in flight (was 8 edges, 64 x 4B loads each).
//    4x fewer load instructions per edge; cross-group shfl_xor reduction.
// ---------------------------------------------------------------------------
#define FMA8(u, cc) do { \
    acc0 += (cc) * __uint_as_float((unsigned)(u).x << 16); \
    acc1 += (cc) * __uint_as_float((unsigned)(u).x & 0xffff0000u); \
    acc2 += (cc) * __uint_as_float((unsigned)(u).y << 16); \
    acc3 += (cc) * __uint_as_float((unsigned)(u).y & 0xffff0000u); \
    acc4 += (cc) * __uint_as_float((unsigned)(u).z << 16); \
    acc5 += (cc) * __uint_as_float((unsigned)(u).z & 0xffff0000u); \
    acc6 += (cc) * __uint_as_float((unsigned)(u).w << 16); \
    acc7 += (cc) * __uint_as_float((unsigned)(u).w & 0xffff0000u); } while (0)

__global__ __launch_bounds__(256) void k_spmm4(const int* __restrict__ row_ptr,
                        const int2* __restrict__ pk_s,
                        const float* __restrict__ rinv_in, const int4* __restrict__ hb4,
                        int4* __restrict__ Tb4, int node0) {
    int r    = threadIdx.x >> 6;          // wave index = relation
    int lane = threadIdx.x & 63;
    int g    = lane >> 4;                 // edge sub-group 0..3
    int m    = lane & 15;                 // owns features [8m, 8m+8)
    int nl   = blockIdx.x;                // local row within half
    int node = node0 + nl;
    int k0 = row_ptr[r * (N_NODE + 1) + node];
    int k1 = row_ptr[r * (N_NODE + 1) + node + 1];
    const int2* pp = pk_s + (size_t)r * N_EDGE;
    float acc0 = 0.f, acc1 = 0.f, acc2 = 0.f, acc3 = 0.f;
    float acc4 = 0.f, acc5 = 0.f, acc6 = 0.f, acc7 = 0.f;
    int k = k0 + g;                       // this group's edge stream (stride 4)
    for (; k + 12 < k1; k += 16) {        // 16 edges per wave-step
        int2 pA = pp[k], pB = pp[k + 4], pC = pp[k + 8], pD = pp[k + 12];
        int4 uA = hb4[(size_t)pA.x * 16 + m];
        int4 uB = hb4[(size_t)pB.x * 16 + m];
        int4 uC = hb4[(size_t)pC.x * 16 + m];
        int4 uD = hb4[(size_t)pD.x * 16 + m];
        float cA = __int_as_float(pA.y), cB = __int_as_float(pB.y);
        float cC = __int_as_float(pC.y), cD = __int_as_float(pD.y);
        FMA8(uA, cA);
        FMA8(uB, cB);
        FMA8(uC, cC);
        FMA8(uD, cD);
    }
    for (; k < k1; k += 4) {              // up to 3 tail steps (4 edges each)
        int2 pA = pp[k];
        int4 uA = hb4[(size_t)pA.x * 16 + m];
        FMA8(uA, __int_as_float(pA.y));
    }
    // reduce the 4 edge sub-groups (lanes m, m+16, m+32, m+48)
    acc0 += __shfl_xor(acc0, 16); acc1 += __shfl_xor(acc1, 16);
    acc2 += __shfl_xor(acc2, 16); acc3 += __shfl_xor(acc3, 16);
    acc4 += __shfl_xor(acc4, 16); acc5 += __shfl_xor(acc5, 16);
    acc6 += __shfl_xor(acc6, 16); acc7 += __shfl_xor(acc7, 16);
    acc0 += __shfl_xor(acc0, 32); acc1 += __shfl_xor(acc1, 32);
    acc2 += __shfl_xor(acc2, 32); acc3 += __shfl_xor(acc3, 32);
    acc4 += __shfl_xor(acc4, 32); acc5 += __shfl_xor(acc5, 32);
    acc6 += __shfl_xor(acc6, 32); acc7 += __shfl_xor(acc7, 32);
    if (g == 0) {
        float ri = rinv_in[r * N_NODE + node];
        int4 o;
        o.x = (int)(((unsigned)f2bf(acc1 * ri) << 16) | (unsigned)f2bf(acc0 * ri));
        o.y = (int)(((unsigned)f2bf(acc3 * ri) << 16) | (unsigned)f2bf(acc2 * ri));
        o.z = (int)(((unsigned)f2bf(acc5 * ri) << 16) | (unsigned)f2bf(acc4 * ri));
        o.w = (int)(((unsigned)f2bf(acc7 * ri) << 16) | (unsigned)f2bf(acc6 * ri));
        Tb4[(size_t)nl * 64 + r * 16 + m] = o;   // same 512-bf16 row layout
    }
}

// ---------------------------------------------------------------------------
// 9) MFMA GEMM: out[HALF_N,128] = relu(T[HALF_N,512] @ Wcat[512,128] + bias_sum)
//    mfma_f32_16x16x32_bf16; verified frag layouts (A: m=lane&15,k=(lane>>4)*8+j;
//    C/D: col=lane&15, row=(lane>>4)*4+reg). WT (128KB) L2-resident, no LDS.
// ---------------------------------------------------------------------------
__global__ __launch_bounds__(256) void k_gemm(const unsigned short* __restrict__ Tb,
                                              const unsigned short* __restrict__ WT,
                                              const float* __restrict__ b,
                                              float* __restrict__ outf,
                                              unsigned short* __restrict__ outb,
                                              int node0) {
    int lane = threadIdx.x & 63;
    int wv   = threadIdx.x >> 6;
    int row0 = blockIdx.x * 64 + wv * 16;
    if (row0 >= HALF_N) return;            // HALF_N % 16 == 0: full-or-empty
    int m  = lane & 15;
    int kg = lane >> 4;

    f32x4 acc[8];
#pragma unroll
    for (int t = 0; t < 8; ++t) acc[t] = (f32x4){0.f, 0.f, 0.f, 0.f};

    const unsigned short* arow = Tb + (size_t)(row0 + m) * KDIM + kg * 8;
    for (int k0 = 0; k0 < KDIM; k0 += 32) {
        bf16x8 af = *(const bf16x8*)(arow + k0);
#pragma unroll
        for (int t = 0; t < 8; ++t) {
            bf16x8 bf = *(const bf16x8*)(WT + (size_t)(t * 16 + m) * KDIM + k0 + kg * 8);
            acc[t] = __builtin_amdgcn_mfma_f32_16x16x32_bf16(af, bf, acc[t], 0, 0, 0);
        }
    }

    int rbase = row0 + kg * 4;
#pragma unroll
    for (int t = 0; t < 8; ++t) {
        int col = t * 16 + m;
        float bs = b[col] + b[DIM + col] + b[2 * DIM + col] + b[3 * DIM + col];
#pragma unroll
        for (int rg = 0; rg < 4; ++rg) {
            float v = acc[t][rg] + bs;
            v = v > 0.f ? v : 0.f;         // relu in BOTH layers per reference
            size_t o = (size_t)(node0 + rbase + rg) * DIM + col;
            if (outb) outb[o] = f2bf(v);
            else      outf[o] = v;
        }
    }
}

// ---------------------------------------------------------------------------
extern "C" void kernel_launch(void* const* d_in, const int* in_sizes, int n_in,
                              void* d_out, int out_size, void* d_ws, size_t ws_size,
                              hipStream_t stream) {
    const float* x   = (const float*)d_in[0];
    const int*   src = (const int*)  d_in[1];
    const int*   dst = (const int*)  d_in[2];
    const float* ew  = (const float*)d_in[3];
    const float* W1  = (const float*)d_in[4];
    const float* b1  = (const float*)d_in[5];
    const float* W2  = (const float*)d_in[6];
    const float* b2  = (const float*)d_in[7];
    float* out = (float*)d_out;

    // Workspace carve-up (~162 MB, same proven footprint).
    char* p = (char*)d_ws;
    auto alloc = [&](size_t bytes) -> char* {
        char* q = p;
        p += (bytes + 255) & ~(size_t)255;
        return q;
    };
    const size_t RN = (size_t)N_REL * N_NODE;
    int*   cnt_in     = (int*)  alloc(RN * 4);
    float* rinv_out   = (float*)alloc(RN * 4);
    float* rinv_in    = (float*)alloc(RN * 4);
    int*   row_ptr    = (int*)  alloc((size_t)N_REL * (N_NODE + 1) * 4);
    int*   partials   = (int*)  alloc(N_REL * NCH * 4);
    int*   chunk_base = (int*)  alloc(N_REL * NCH * 4);
    unsigned short* WT1b = (unsigned short*)alloc((size_t)KDIM * DIM * 2);  // 128KB
    unsigned short* WT2b = (unsigned short*)alloc((size_t)KDIM * DIM * 2);  // 128KB
    int2*  pk_s       = (int2*) alloc((size_t)N_REL * N_EDGE * 8);          // 51.2 MB
    char*  Treg       =         alloc((size_t)HALF_N * KDIM * 2);           // 51.2 MB
    char*  hreg       =         alloc((size_t)N_REL * NCHUNK * N_NODE * 4); // 51.2 MB

    // Aliases:
    // Pd (dst partials -> CSR bases) in Treg: dead after k_scatter5, before spmm.
    // Ps (src partials) in hreg: dead after k_reduce_rinv; then hreg splits:
    //   [0, 25.6MB)   h_mid_b : bf16 layer-1 output
    //   [25.6, 51.2)  xb      : bf16 copy of x
    int* Pd = (int*)Treg;
    int* Ps = (int*)hreg;
    unsigned short* h_mid_b = (unsigned short*)hreg;
    unsigned short* xb      = (unsigned short*)(hreg + (size_t)N_NODE * DIM * 2);
    unsigned short* Tb      = (unsigned short*)Treg;

    dim3 gridH(NCHUNK, NTILE, N_REL);   // 32 x 4 x 4 = 512 blocks of 512 thr
    k_hist<<<gridH, 512, 0, stream>>>(dst, Pd);
    k_hist<<<gridH, 512, 0, stream>>>(src, Ps);
    k_reduce_rinv<<<((int)RN + 255) / 256, 256, 0, stream>>>(Pd, Ps, cnt_in, rinv_in, rinv_out);
    k_cvt<<<(N_NODE * DIM / 4 + 255) / 256, 256, 0, stream>>>(x, xb);  // Ps dead
    k_cvt_w<<<(KDIM * DIM + 255) / 256, 256, 0, stream>>>(W1, WT1b);
    k_cvt_w<<<(KDIM * DIM + 255) / 256, 256, 0, stream>>>(W2, WT2b);
    k_chunk_sum<<<dim3(NCH, N_REL), 256, 0, stream>>>(cnt_in, partials);
    k_scan_partials<<<1, 256, 0, stream>>>(partials, chunk_base, row_ptr);
    k_chunk_scan<<<dim3(NCH, N_REL), 256, 0, stream>>>(cnt_in, chunk_base, row_ptr);
    k_base<<<((int)RN + 255) / 256, 256, 0, stream>>>(Pd, row_ptr);
    k_scatter5<<<gridH, 512, 0, stream>>>(src, dst, ew, Pd, rinv_out, pk_s);

    const int spmm_grid = HALF_N;              // one node per block, 4 r-waves
    const int gemm_grid = (HALF_N + 63) / 64;  // 782

    // layer 1: xb (bf16) -> h_mid_b (bf16), two halves through Tb
    for (int h = 0; h < 2; ++h) {
        k_spmm4<<<spmm_grid, 256, 0, stream>>>(row_ptr, pk_s, rinv_in,
                                               (const int4*)xb, (int4*)Tb, h * HALF_N);
        k_gemm<<<gemm_grid, 256, 0, stream>>>(Tb, WT1b, b1, (float*)nullptr, h_mid_b, h * HALF_N);
    }
    // layer 2: h_mid_b (bf16) -> out (fp32)
    for (int h = 0; h < 2; ++h) {
        k_spmm4<<<spmm_grid, 256, 0, stream>>>(row_ptr, pk_s, rinv_in,
                                               (const int4*)h_mid_b, (int4*)Tb, h * HALF_N);
        k_gemm<<<gemm_grid, 256, 0, stream>>>(Tb, WT2b, b2, out, (unsigned short*)nullptr, h * HALF_N);
    }
}

// Round 3
// 1276.812 us; speedup vs baseline: 1.5397x; 1.0061x over previous
//
#include <hip/hip_runtime.h>
#include <hip/hip_bf16.h>
#include <cstdint>
#include <cstddef>

// Problem constants
#define N_NODE 100000
#define N_EDGE 1600000
#define N_REL  4
#define DIM    128
#define KDIM   512                               // N_REL * DIM stacked
#define HALF_N 50000
#define CHUNK  2048
#define NCH    ((N_NODE + CHUNK - 1) / CHUNK)   // 49

// Histogram/scatter tiling: packed u16 counters -> TS=25000 in 50KB LDS,
// 4 passes. 512-thread blocks; grid 512 = 2 blocks/CU (grid-capped).
// (Global-atomic variant is 2x WORSE: cross-XCD RMW = 400MB HBM write.)
#define CH_E   50000                             // edges per chunk (div by 8)
#define NCHUNK 32                                // chunks (Pd table caps this)
#define TS     25000                             // node-tile size (even)
#define NTILE  4                                 // ceil(100000/25000)

typedef __attribute__((ext_vector_type(8))) short bf16x8;   // 8 bf16 (4 VGPRs)
typedef __attribute__((ext_vector_type(4))) float f32x4;    // 4 fp32 acc

__device__ inline unsigned short f2bf(float f) {
    __hip_bfloat16 b = __float2bfloat16(f);
    return *reinterpret_cast<unsigned short*>(&b);
}

// ---------------------------------------------------------------------------
// 1) Tiled LDS histogram, packed u16 fields (count <= 50000 < 2^16).
//    8 edges per thread-iteration for deeper load pipelining.
// ---------------------------------------------------------------------------
__global__ __launch_bounds__(512) void k_hist(const int* __restrict__ idx,
                                              int* __restrict__ P) {
    __shared__ unsigned hist[TS / 2];            // 50 KB
    int c = blockIdx.x, t = blockIdx.y, r = blockIdx.z;
    for (int i = threadIdx.x; i < TS / 2; i += 512) hist[i] = 0;
    __syncthreads();
    int n0 = t * TS;
    const int4* ip = (const int4*)(idx + (size_t)r * N_EDGE + c * CH_E);
    for (int q = threadIdx.x * 2; q < CH_E / 4; q += 1024) {
        int4 d0 = ip[q], d1 = ip[q + 1];
        int dd[8] = {d0.x, d0.y, d0.z, d0.w, d1.x, d1.y, d1.z, d1.w};
#pragma unroll
        for (int i = 0; i < 8; ++i) {
            unsigned a = (unsigned)(dd[i] - n0);
            if (a < TS) atomicAdd(&hist[a >> 1], 1u << (16 * (a & 1)));
        }
    }
    __syncthreads();
    int* Pp = P + ((size_t)r * NCHUNK + c) * N_NODE;
    for (int i = threadIdx.x; i < TS; i += 512) {
        int n = n0 + i;
        if (n < N_NODE)
            Pp[n] = (int)((hist[i >> 1] >> (16 * (i & 1))) & 0xffffu);
    }
}

// 2) Reduce partials over chunks -> cnt_in (for scan) + rinv_in/out
__global__ void k_reduce_rinv(const int* __restrict__ Pd, const int* __restrict__ Ps,
                              int* __restrict__ cnt_in, float* __restrict__ rinv_in,
                              float* __restrict__ rinv_out) {
    int i = blockIdx.x * blockDim.x + threadIdx.x;   // r*N + n
    if (i >= N_REL * N_NODE) return;
    int r = i / N_NODE, n = i - r * N_NODE;
    int ci = 0, co = 0;
#pragma unroll
    for (int c = 0; c < NCHUNK; ++c) {
        ci += Pd[((size_t)r * NCHUNK + c) * N_NODE + n];
        co += Ps[((size_t)r * NCHUNK + c) * N_NODE + n];
    }
    cnt_in[i]   = ci;
    rinv_in[i]  = rsqrtf((float)max(ci, 1));
    rinv_out[i] = rsqrtf((float)max(co, 1));
}

// ---------------------------------------------------------------------------
// 3) CSR-by-dst row_ptr: chunk sums -> scan partials -> chunk scan
// ---------------------------------------------------------------------------
__global__ void k_chunk_sum(const int* __restrict__ cnt_in, int* __restrict__ partials) {
    int r = blockIdx.y, ch = blockIdx.x;
    __shared__ int sdata[256];
    int s = 0;
    for (int i = 0; i < CHUNK / 256; ++i) {
        int n = ch * CHUNK + i * 256 + threadIdx.x;
        if (n < N_NODE) s += cnt_in[r * N_NODE + n];
    }
    sdata[threadIdx.x] = s;
    __syncthreads();
    for (int off = 128; off > 0; off >>= 1) {
        if (threadIdx.x < off) sdata[threadIdx.x] += sdata[threadIdx.x + off];
        __syncthreads();
    }
    if (threadIdx.x == 0) partials[r * NCH + ch] = sdata[0];
}

__global__ void k_scan_partials(const int* __restrict__ partials,
                                int* __restrict__ chunk_base, int* __restrict__ row_ptr) {
    __shared__ int sp[N_REL * NCH];
    int t = threadIdx.x;
    if (t < N_REL * NCH) sp[t] = partials[t];
    __syncthreads();
    if (t == 0) {
        for (int r = 0; r < N_REL; ++r) {
            int run = 0;
            for (int ch = 0; ch < NCH; ++ch) {
                chunk_base[r * NCH + ch] = run;
                run += sp[r * NCH + ch];
            }
            row_ptr[r * (N_NODE + 1) + N_NODE] = N_EDGE;
        }
    }
}

__global__ void k_chunk_scan(const int* __restrict__ cnt_in,
                             const int* __restrict__ chunk_base, int* __restrict__ row_ptr) {
    int r = blockIdx.y, ch = blockIdx.x;
    __shared__ int tsum[256];
    int base_n = ch * CHUNK;
    int vals[8];
    int loc = 0;
    for (int i = 0; i < 8; ++i) {
        int n = base_n + threadIdx.x * 8 + i;
        vals[i] = (n < N_NODE) ? cnt_in[r * N_NODE + n] : 0;
        loc += vals[i];
    }
    tsum[threadIdx.x] = loc;
    __syncthreads();
    for (int off = 1; off < 256; off <<= 1) {     // Hillis-Steele inclusive scan
        int y = (threadIdx.x >= off) ? tsum[threadIdx.x - off] : 0;
        __syncthreads();
        tsum[threadIdx.x] += y;
        __syncthreads();
    }
    int pos = chunk_base[r * NCH + ch] + tsum[threadIdx.x] - loc;  // exclusive
    for (int i = 0; i < 8; ++i) {
        int n = base_n + threadIdx.x * 8 + i;
        if (n < N_NODE) { row_ptr[r * (N_NODE + 1) + n] = pos; pos += vals[i]; }
    }
}

// 4) In-place: P[r][c][n] := row_ptr[r][n] + sum_{c'<c} P[r][c'][n]
__global__ void k_base(int* __restrict__ P, const int* __restrict__ row_ptr) {
    int i = blockIdx.x * blockDim.x + threadIdx.x;
    if (i >= N_REL * N_NODE) return;
    int r = i / N_NODE, n = i - r * N_NODE;
    int run = row_ptr[r * (N_NODE + 1) + n];
#pragma unroll
    for (int c = 0; c < NCHUNK; ++c) {
        size_t o = ((size_t)r * NCHUNK + c) * N_NODE + n;
        int p = P[o];
        P[o] = run;
        run += p;
    }
}

// ---------------------------------------------------------------------------
// 5) Scatter, phase-grouped for MLP: 8 edges/thread/iter. Phase 1 issues all
//    bp[] (clamped, unconditional) + ro[] gathers -> 16 independent loads in
//    flight; phase 2 does conditional LDS-atomic + store. bp/ro gathers do
//    NOT depend on the atomic rank, so they overlap the whole chain.
// ---------------------------------------------------------------------------
__global__ __launch_bounds__(512) void k_scatter5(const int* __restrict__ src,
                          const int* __restrict__ dst, const float* __restrict__ ew,
                          const int* __restrict__ base, const float* __restrict__ rinv_out,
                          int2* __restrict__ pk_s) {
    __shared__ unsigned cur[TS / 2];             // 50 KB, local ranks
    int c = blockIdx.x, t = blockIdx.y, r = blockIdx.z;
    for (int i = threadIdx.x; i < TS / 2; i += 512) cur[i] = 0;
    __syncthreads();
    int n0 = t * TS;
    int e0 = c * CH_E;
    const int*   bp = base + ((size_t)r * NCHUNK + c) * N_NODE + n0;
    const float* ro = rinv_out + (size_t)r * N_NODE;
    size_t roff = (size_t)r * N_EDGE;
    const int4*   dp = (const int4*)  (dst + roff + e0);
    const int4*   sp = (const int4*)  (src + roff + e0);
    const float4* wp = (const float4*)(ew  + roff + e0);
    for (int q = threadIdx.x * 2; q < CH_E / 4; q += 1024) {
        int4   d0 = dp[q], d1 = dp[q + 1];
        int4   s0 = sp[q], s1 = sp[q + 1];
        float4 w0 = wp[q], w1 = wp[q + 1];
        int   dd[8] = {d0.x, d0.y, d0.z, d0.w, d1.x, d1.y, d1.z, d1.w};
        int   ss[8] = {s0.x, s0.y, s0.z, s0.w, s1.x, s1.y, s1.z, s1.w};
        float ww[8] = {w0.x, w0.y, w0.z, w0.w, w1.x, w1.y, w1.z, w1.w};
        unsigned aa[8]; int bb[8]; float cc[8];
#pragma unroll
        for (int i = 0; i < 8; ++i) {
            aa[i] = (unsigned)(dd[i] - n0);
            unsigned ac = aa[i] < TS ? aa[i] : 0u;   // clamp -> unconditional load
            bb[i] = bp[ac];                          // independent L1/L2 gather
            cc[i] = ww[i] * ro[ss[i]];               // independent L2 gather
        }
#pragma unroll
        for (int i = 0; i < 8; ++i) {
            if (aa[i] < TS) {
                unsigned old = atomicAdd(&cur[aa[i] >> 1], 1u << (16 * (aa[i] & 1)));
                int rank = (int)((old >> (16 * (aa[i] & 1))) & 0xffffu);
                pk_s[roff + bb[i] + rank] = make_int2(ss[i], __float_as_int(cc[i]));
            }
        }
    }
}

// 7a) fp32 -> bf16 matrix convert (4 elems/thread)
__global__ void k_cvt(const float* __restrict__ x, unsigned short* __restrict__ xb) {
    int i = blockIdx.x * blockDim.x + threadIdx.x;
    if (i >= N_NODE * DIM / 4) return;
    float4 v = ((const float4*)x)[i];
    ushort4 o;
    o.x = f2bf(v.x); o.y = f2bf(v.y); o.z = f2bf(v.z); o.w = f2bf(v.w);
    ((ushort4*)xb)[i] = o;
}

// 7b) W [512][128] fp32 -> WT [128][512] bf16 (transpose for B-frag loads)
__global__ void k_cvt_w(const float* __restrict__ W, unsigned short* __restrict__ WT) {
    int i = blockIdx.x * blockDim.x + threadIdx.x;
    if (i >= KDIM * DIM) return;
    int k = i >> 7, j = i & 127;
    WT[(size_t)j * KDIM + k] = f2bf(W[i]);
}

// ---------------------------------------------------------------------------
// 8) Fused SpMM, wide-gather: lane owns a 16B (dwordx4) slice of the 256B
//    feature row; 16 lanes/row => 4 edges in flight per wave-step, 4-deep
//    unroll = 16 edges in flight. Cross-group shfl_xor reduction at end.
// ---------------------------------------------------------------------------
#define FMA8(u, cc) do { \
    acc0 += (cc) * __uint_as_float((unsigned)(u).x << 16); \
    acc1 += (cc) * __uint_as_float((unsigned)(u).x & 0xffff0000u); \
    acc2 += (cc) * __uint_as_float((unsigned)(u).y << 16); \
    acc3 += (cc) * __uint_as_float((unsigned)(u).y & 0xffff0000u); \
    acc4 += (cc) * __uint_as_float((unsigned)(u).z << 16); \
    acc5 += (cc) * __uint_as_float((unsigned)(u).z & 0xffff0000u); \
    acc6 += (cc) * __uint_as_float((unsigned)(u).w << 16); \
    acc7 += (cc) * __uint_as_float((unsigned)(u).w & 0xffff0000u); } while (0)

__global__ __launch_bounds__(256) void k_spmm4(const int* __restrict__ row_ptr,
                        const int2* __restrict__ pk_s,
                        const float* __restrict__ rinv_in, const int4* __restrict__ hb4,
                        int4* __restrict__ Tb4, int node0) {
    int r    = threadIdx.x >> 6;          // wave index = relation
    int lane = threadIdx.x & 63;
    int g    = lane >> 4;                 // edge sub-group 0..3
    int m    = lane & 15;                 // owns features [8m, 8m+8)
    int nl   = blockIdx.x;                // local row within half
    int node = node0 + nl;
    int k0 = row_ptr[r * (N_NODE + 1) + node];
    int k1 = row_ptr[r * (N_NODE + 1) + node + 1];
    const int2* pp = pk_s + (size_t)r * N_EDGE;
    float acc0 = 0.f, acc1 = 0.f, acc2 = 0.f, acc3 = 0.f;
    float acc4 = 0.f, acc5 = 0.f, acc6 = 0.f, acc7 = 0.f;
    int k = k0 + g;                       // this group's edge stream (stride 4)
    for (; k + 12 < k1; k += 16) {        // 16 edges per wave-step
        int2 pA = pp[k], pB = pp[k + 4], pC = pp[k + 8], pD = pp[k + 12];
        int4 uA = hb4[(size_t)pA.x * 16 + m];
        int4 uB = hb4[(size_t)pB.x * 16 + m];
        int4 uC = hb4[(size_t)pC.x * 16 + m];
        int4 uD = hb4[(size_t)pD.x * 16 + m];
        float cA = __int_as_float(pA.y), cB = __int_as_float(pB.y);
        float cC = __int_as_float(pC.y), cD = __int_as_float(pD.y);
        FMA8(uA, cA);
        FMA8(uB, cB);
        FMA8(uC, cC);
        FMA8(uD, cD);
    }
    for (; k < k1; k += 4) {              // up to 3 tail steps (4 edges each)
        int2 pA = pp[k];
        int4 uA = hb4[(size_t)pA.x * 16 + m];
        FMA8(uA, __int_as_float(pA.y));
    }
    // reduce the 4 edge sub-groups (lanes m, m+16, m+32, m+48)
    acc0 += __shfl_xor(acc0, 16); acc1 += __shfl_xor(acc1, 16);
    acc2 += __shfl_xor(acc2, 16); acc3 += __shfl_xor(acc3, 16);
    acc4 += __shfl_xor(acc4, 16); acc5 += __shfl_xor(acc5, 16);
    acc6 += __shfl_xor(acc6, 16); acc7 += __shfl_xor(acc7, 16);
    acc0 += __shfl_xor(acc0, 32); acc1 += __shfl_xor(acc1, 32);
    acc2 += __shfl_xor(acc2, 32); acc3 += __shfl_xor(acc3, 32);
    acc4 += __shfl_xor(acc4, 32); acc5 += __shfl_xor(acc5, 32);
    acc6 += __shfl_xor(acc6, 32); acc7 += __shfl_xor(acc7, 32);
    if (g == 0) {
        float ri = rinv_in[r * N_NODE + node];
        int4 o;
        o.x = (int)(((unsigned)f2bf(acc1 * ri) << 16) | (unsigned)f2bf(acc0 * ri));
        o.y = (int)(((unsigned)f2bf(acc3 * ri) << 16) | (unsigned)f2bf(acc2 * ri));
        o.z = (int)(((unsigned)f2bf(acc5 * ri) << 16) | (unsigned)f2bf(acc4 * ri));
        o.w = (int)(((unsigned)f2bf(acc7 * ri) << 16) | (unsigned)f2bf(acc6 * ri));
        Tb4[(size_t)nl * 64 + r * 16 + m] = o;   // same 512-bf16 row layout
    }
}

// ---------------------------------------------------------------------------
// 9) MFMA GEMM: out[HALF_N,128] = relu(T[HALF_N,512] @ Wcat[512,128] + bias_sum)
//    mfma_f32_16x16x32_bf16; verified frag layouts (A: m=lane&15,k=(lane>>4)*8+j;
//    C/D: col=lane&15, row=(lane>>4)*4+reg). WT (128KB) L2-resident, no LDS.
// ---------------------------------------------------------------------------
__global__ __launch_bounds__(256) void k_gemm(const unsigned short* __restrict__ Tb,
                                              const unsigned short* __restrict__ WT,
                                              const float* __restrict__ b,
                                              float* __restrict__ outf,
                                              unsigned short* __restrict__ outb,
                                              int node0) {
    int lane = threadIdx.x & 63;
    int wv   = threadIdx.x >> 6;
    int row0 = blockIdx.x * 64 + wv * 16;
    if (row0 >= HALF_N) return;            // HALF_N % 16 == 0: full-or-empty
    int m  = lane & 15;
    int kg = lane >> 4;

    f32x4 acc[8];
#pragma unroll
    for (int t = 0; t < 8; ++t) acc[t] = (f32x4){0.f, 0.f, 0.f, 0.f};

    const unsigned short* arow = Tb + (size_t)(row0 + m) * KDIM + kg * 8;
    for (int k0 = 0; k0 < KDIM; k0 += 32) {
        bf16x8 af = *(const bf16x8*)(arow + k0);
#pragma unroll
        for (int t = 0; t < 8; ++t) {
            bf16x8 bf = *(const bf16x8*)(WT + (size_t)(t * 16 + m) * KDIM + k0 + kg * 8);
            acc[t] = __builtin_amdgcn_mfma_f32_16x16x32_bf16(af, bf, acc[t], 0, 0, 0);
        }
    }

    int rbase = row0 + kg * 4;
#pragma unroll
    for (int t = 0; t < 8; ++t) {
        int col = t * 16 + m;
        float bs = b[col] + b[DIM + col] + b[2 * DIM + col] + b[3 * DIM + col];
#pragma unroll
        for (int rg = 0; rg < 4; ++rg) {
            float v = acc[t][rg] + bs;
            v = v > 0.f ? v : 0.f;         // relu in BOTH layers per reference
            size_t o = (size_t)(node0 + rbase + rg) * DIM + col;
            if (outb) outb[o] = f2bf(v);
            else      outf[o] = v;
        }
    }
}

// ---------------------------------------------------------------------------
extern "C" void kernel_launch(void* const* d_in, const int* in_sizes, int n_in,
                              void* d_out, int out_size, void* d_ws, size_t ws_size,
                              hipStream_t stream) {
    const float* x   = (const float*)d_in[0];
    const int*   src = (const int*)  d_in[1];
    const int*   dst = (const int*)  d_in[2];
    const float* ew  = (const float*)d_in[3];
    const float* W1  = (const float*)d_in[4];
    const float* b1  = (const float*)d_in[5];
    const float* W2  = (const float*)d_in[6];
    const float* b2  = (const float*)d_in[7];
    float* out = (float*)d_out;

    // Workspace carve-up (~162 MB, same proven footprint).
    char* p = (char*)d_ws;
    auto alloc = [&](size_t bytes) -> char* {
        char* q = p;
        p += (bytes + 255) & ~(size_t)255;
        return q;
    };
    const size_t RN = (size_t)N_REL * N_NODE;
    int*   cnt_in     = (int*)  alloc(RN * 4);
    float* rinv_out   = (float*)alloc(RN * 4);
    float* rinv_in    = (float*)alloc(RN * 4);
    int*   row_ptr    = (int*)  alloc((size_t)N_REL * (N_NODE + 1) * 4);
    int*   partials   = (int*)  alloc(N_REL * NCH * 4);
    int*   chunk_base = (int*)  alloc(N_REL * NCH * 4);
    unsigned short* WT1b = (unsigned short*)alloc((size_t)KDIM * DIM * 2);  // 128KB
    unsigned short* WT2b = (unsigned short*)alloc((size_t)KDIM * DIM * 2);  // 128KB
    int2*  pk_s       = (int2*) alloc((size_t)N_REL * N_EDGE * 8);          // 51.2 MB
    char*  Treg       =         alloc((size_t)HALF_N * KDIM * 2);           // 51.2 MB
    char*  hreg       =         alloc((size_t)N_REL * NCHUNK * N_NODE * 4); // 51.2 MB

    // Aliases:
    // Pd (dst partials -> CSR bases) in Treg: dead after k_scatter5, before spmm.
    // Ps (src partials) in hreg: dead after k_reduce_rinv; then hreg splits:
    //   [0, 25.6MB)   h_mid_b : bf16 layer-1 output
    //   [25.6, 51.2)  xb      : bf16 copy of x
    int* Pd = (int*)Treg;
    int* Ps = (int*)hreg;
    unsigned short* h_mid_b = (unsigned short*)hreg;
    unsigned short* xb      = (unsigned short*)(hreg + (size_t)N_NODE * DIM * 2);
    unsigned short* Tb      = (unsigned short*)Treg;

    dim3 gridH(NCHUNK, NTILE, N_REL);   // 32 x 4 x 4 = 512 blocks of 512 thr
    k_hist<<<gridH, 512, 0, stream>>>(dst, Pd);
    k_hist<<<gridH, 512, 0, stream>>>(src, Ps);
    k_reduce_rinv<<<((int)RN + 255) / 256, 256, 0, stream>>>(Pd, Ps, cnt_in, rinv_in, rinv_out);
    k_cvt<<<(N_NODE * DIM / 4 + 255) / 256, 256, 0, stream>>>(x, xb);  // Ps dead
    k_cvt_w<<<(KDIM * DIM + 255) / 256, 256, 0, stream>>>(W1, WT1b);
    k_cvt_w<<<(KDIM * DIM + 255) / 256, 256, 0, stream>>>(W2, WT2b);
    k_chunk_sum<<<dim3(NCH, N_REL), 256, 0, stream>>>(cnt_in, partials);
    k_scan_partials<<<1, 256, 0, stream>>>(partials, chunk_base, row_ptr);
    k_chunk_scan<<<dim3(NCH, N_REL), 256, 0, stream>>>(cnt_in, chunk_base, row_ptr);
    k_base<<<((int)RN + 255) / 256, 256, 0, stream>>>(Pd, row_ptr);
    k_scatter5<<<gridH, 512, 0, stream>>>(src, dst, ew, Pd, rinv_out, pk_s);

    const int spmm_grid = HALF_N;              // one node per block, 4 r-waves
    const int gemm_grid = (HALF_N + 63) / 64;  // 782

    // layer 1: xb (bf16) -> h_mid_b (bf16), two halves through Tb
    for (int h = 0; h < 2; ++h) {
        k_spmm4<<<spmm_grid, 256, 0, stream>>>(row_ptr, pk_s, rinv_in,
                                               (const int4*)xb, (int4*)Tb, h * HALF_N);
        k_gemm<<<gemm_grid, 256, 0, stream>>>(Tb, WT1b, b1, (float*)nullptr, h_mid_b, h * HALF_N);
    }
    // layer 2: h_mid_b (bf16) -> out (fp32)
    for (int h = 0; h < 2; ++h) {
        k_spmm4<<<spmm_grid, 256, 0, stream>>>(row_ptr, pk_s, rinv_in,
                                               (const int4*)h_mid_b, (int4*)Tb, h * HALF_N);
        k_gemm<<<gemm_grid, 256, 0, stream>>>(Tb, WT2b, b2, out, (unsigned short*)nullptr, h * HALF_N);
    }
}

// Round 4
// 1222.468 us; speedup vs baseline: 1.6081x; 1.0445x over previous
//
#include <hip/hip_runtime.h>
#include <hip/hip_bf16.h>
#include <cstdint>
#include <cstddef>

// Problem constants
#define N_NODE 100000
#define N_EDGE 1600000
#define N_REL  4
#define DIM    128
#define KDIM   512                               // N_REL * DIM stacked
#define HALF_N 50000
#define CHUNK  2048
#define NCH    ((N_NODE + CHUNK - 1) / CHUNK)   // 49

// Histogram/scatter tiling: packed u16 counters -> TS=25000 in 50KB LDS,
// 4 passes. 512-thread blocks; grid 512 = 2 blocks/CU (grid-capped).
// (Global-atomic variant is 2x WORSE: cross-XCD RMW = 400MB HBM write.
//  Phase-grouped prefetch variant: FETCH -90MB but +9us -> NOT BW-bound.)
#define CH_E   50000                             // edges per chunk (div by 8)
#define NCHUNK 32                                // chunks (Pd table caps this)
#define TS     25000                             // node-tile size (even)
#define NTILE  4                                 // ceil(100000/25000)

typedef __attribute__((ext_vector_type(8))) short bf16x8;   // 8 bf16 (4 VGPRs)
typedef __attribute__((ext_vector_type(4))) float f32x4;    // 4 fp32 acc

__device__ inline unsigned short f2bf(float f) {
    __hip_bfloat16 b = __float2bfloat16(f);
    return *reinterpret_cast<unsigned short*>(&b);
}

// ---------------------------------------------------------------------------
// 1) Tiled LDS histogram, packed u16 fields (count <= 50000 < 2^16).
//    8 edges per thread-iteration for deeper load pipelining.
// ---------------------------------------------------------------------------
__global__ __launch_bounds__(512) void k_hist(const int* __restrict__ idx,
                                              int* __restrict__ P) {
    __shared__ unsigned hist[TS / 2];            // 50 KB
    int c = blockIdx.x, t = blockIdx.y, r = blockIdx.z;
    for (int i = threadIdx.x; i < TS / 2; i += 512) hist[i] = 0;
    __syncthreads();
    int n0 = t * TS;
    const int4* ip = (const int4*)(idx + (size_t)r * N_EDGE + c * CH_E);
    for (int q = threadIdx.x * 2; q < CH_E / 4; q += 1024) {
        int4 d0 = ip[q], d1 = ip[q + 1];
        int dd[8] = {d0.x, d0.y, d0.z, d0.w, d1.x, d1.y, d1.z, d1.w};
#pragma unroll
        for (int i = 0; i < 8; ++i) {
            unsigned a = (unsigned)(dd[i] - n0);
            if (a < TS) atomicAdd(&hist[a >> 1], 1u << (16 * (a & 1)));
        }
    }
    __syncthreads();
    int* Pp = P + ((size_t)r * NCHUNK + c) * N_NODE;
    for (int i = threadIdx.x; i < TS; i += 512) {
        int n = n0 + i;
        if (n < N_NODE)
            Pp[n] = (int)((hist[i >> 1] >> (16 * (i & 1))) & 0xffffu);
    }
}

// 2) Reduce partials over chunks -> cnt_in (for scan) + rinv_in/out
__global__ void k_reduce_rinv(const int* __restrict__ Pd, const int* __restrict__ Ps,
                              int* __restrict__ cnt_in, float* __restrict__ rinv_in,
                              float* __restrict__ rinv_out) {
    int i = blockIdx.x * blockDim.x + threadIdx.x;   // r*N + n
    if (i >= N_REL * N_NODE) return;
    int r = i / N_NODE, n = i - r * N_NODE;
    int ci = 0, co = 0;
#pragma unroll
    for (int c = 0; c < NCHUNK; ++c) {
        ci += Pd[((size_t)r * NCHUNK + c) * N_NODE + n];
        co += Ps[((size_t)r * NCHUNK + c) * N_NODE + n];
    }
    cnt_in[i]   = ci;
    rinv_in[i]  = rsqrtf((float)max(ci, 1));
    rinv_out[i] = rsqrtf((float)max(co, 1));
}

// ---------------------------------------------------------------------------
// 3) CSR-by-dst row_ptr: chunk sums -> scan partials -> chunk scan
// ---------------------------------------------------------------------------
__global__ void k_chunk_sum(const int* __restrict__ cnt_in, int* __restrict__ partials) {
    int r = blockIdx.y, ch = blockIdx.x;
    __shared__ int sdata[256];
    int s = 0;
    for (int i = 0; i < CHUNK / 256; ++i) {
        int n = ch * CHUNK + i * 256 + threadIdx.x;
        if (n < N_NODE) s += cnt_in[r * N_NODE + n];
    }
    sdata[threadIdx.x] = s;
    __syncthreads();
    for (int off = 128; off > 0; off >>= 1) {
        if (threadIdx.x < off) sdata[threadIdx.x] += sdata[threadIdx.x + off];
        __syncthreads();
    }
    if (threadIdx.x == 0) partials[r * NCH + ch] = sdata[0];
}

__global__ void k_scan_partials(const int* __restrict__ partials,
                                int* __restrict__ chunk_base, int* __restrict__ row_ptr) {
    __shared__ int sp[N_REL * NCH];
    int t = threadIdx.x;
    if (t < N_REL * NCH) sp[t] = partials[t];
    __syncthreads();
    if (t == 0) {
        for (int r = 0; r < N_REL; ++r) {
            int run = 0;
            for (int ch = 0; ch < NCH; ++ch) {
                chunk_base[r * NCH + ch] = run;
                run += sp[r * NCH + ch];
            }
            row_ptr[r * (N_NODE + 1) + N_NODE] = N_EDGE;
        }
    }
}

__global__ void k_chunk_scan(const int* __restrict__ cnt_in,
                             const int* __restrict__ chunk_base, int* __restrict__ row_ptr) {
    int r = blockIdx.y, ch = blockIdx.x;
    __shared__ int tsum[256];
    int base_n = ch * CHUNK;
    int vals[8];
    int loc = 0;
    for (int i = 0; i < 8; ++i) {
        int n = base_n + threadIdx.x * 8 + i;
        vals[i] = (n < N_NODE) ? cnt_in[r * N_NODE + n] : 0;
        loc += vals[i];
    }
    tsum[threadIdx.x] = loc;
    __syncthreads();
    for (int off = 1; off < 256; off <<= 1) {     // Hillis-Steele inclusive scan
        int y = (threadIdx.x >= off) ? tsum[threadIdx.x - off] : 0;
        __syncthreads();
        tsum[threadIdx.x] += y;
        __syncthreads();
    }
    int pos = chunk_base[r * NCH + ch] + tsum[threadIdx.x] - loc;  // exclusive
    for (int i = 0; i < 8; ++i) {
        int n = base_n + threadIdx.x * 8 + i;
        if (n < N_NODE) { row_ptr[r * (N_NODE + 1) + n] = pos; pos += vals[i]; }
    }
}

// 4) In-place: P[r][c][n] := row_ptr[r][n] + sum_{c'<c} P[r][c'][n]
__global__ void k_base(int* __restrict__ P, const int* __restrict__ row_ptr) {
    int i = blockIdx.x * blockDim.x + threadIdx.x;
    if (i >= N_REL * N_NODE) return;
    int r = i / N_NODE, n = i - r * N_NODE;
    int run = row_ptr[r * (N_NODE + 1) + n];
#pragma unroll
    for (int c = 0; c < NCHUNK; ++c) {
        size_t o = ((size_t)r * NCHUNK + c) * N_NODE + n;
        int p = P[o];
        P[o] = run;
        run += p;
    }
}

// 5) Scatter: packed u16 LOCAL cursors (init 0), CSR base added per-hit via
//    L2-resident 64KB-window gather; rinv_out folded in. (Proven 265us form.)
__global__ __launch_bounds__(512) void k_scatter5(const int* __restrict__ src,
                          const int* __restrict__ dst, const float* __restrict__ ew,
                          const int* __restrict__ base, const float* __restrict__ rinv_out,
                          int2* __restrict__ pk_s) {
    __shared__ unsigned cur[TS / 2];             // 50 KB, local ranks
    int c = blockIdx.x, t = blockIdx.y, r = blockIdx.z;
    for (int i = threadIdx.x; i < TS / 2; i += 512) cur[i] = 0;
    __syncthreads();
    int n0 = t * TS;
    int e0 = c * CH_E;
    const int*   bp = base + ((size_t)r * NCHUNK + c) * N_NODE + n0;
    const float* ro = rinv_out + (size_t)r * N_NODE;
    size_t roff = (size_t)r * N_EDGE;
    for (int e = e0 + threadIdx.x * 4; e < e0 + CH_E; e += 2048) {
        int4   d4 = *(const int4*)  (dst + roff + e);
        int4   s4 = *(const int4*)  (src + roff + e);
        float4 w4 = *(const float4*)(ew  + roff + e);
        unsigned a; unsigned old; int rank;
        a = (unsigned)(d4.x - n0);
        if (a < TS) {
            old = atomicAdd(&cur[a >> 1], 1u << (16 * (a & 1)));
            rank = (int)((old >> (16 * (a & 1))) & 0xffffu);
            pk_s[roff + bp[a] + rank] = make_int2(s4.x, __float_as_int(w4.x * ro[s4.x]));
        }
        a = (unsigned)(d4.y - n0);
        if (a < TS) {
            old = atomicAdd(&cur[a >> 1], 1u << (16 * (a & 1)));
            rank = (int)((old >> (16 * (a & 1))) & 0xffffu);
            pk_s[roff + bp[a] + rank] = make_int2(s4.y, __float_as_int(w4.y * ro[s4.y]));
        }
        a = (unsigned)(d4.z - n0);
        if (a < TS) {
            old = atomicAdd(&cur[a >> 1], 1u << (16 * (a & 1)));
            rank = (int)((old >> (16 * (a & 1))) & 0xffffu);
            pk_s[roff + bp[a] + rank] = make_int2(s4.z, __float_as_int(w4.z * ro[s4.z]));
        }
        a = (unsigned)(d4.w - n0);
        if (a < TS) {
            old = atomicAdd(&cur[a >> 1], 1u << (16 * (a & 1)));
            rank = (int)((old >> (16 * (a & 1))) & 0xffffu);
            pk_s[roff + bp[a] + rank] = make_int2(s4.w, __float_as_int(w4.w * ro[s4.w]));
        }
    }
}

// 7a) fp32 -> bf16 matrix convert (4 elems/thread)
__global__ void k_cvt(const float* __restrict__ x, unsigned short* __restrict__ xb) {
    int i = blockIdx.x * blockDim.x + threadIdx.x;
    if (i >= N_NODE * DIM / 4) return;
    float4 v = ((const float4*)x)[i];
    ushort4 o;
    o.x = f2bf(v.x); o.y = f2bf(v.y); o.z = f2bf(v.z); o.w = f2bf(v.w);
    ((ushort4*)xb)[i] = o;
}

// 7b) W [512][128] fp32 -> WT [128][512] bf16 (transpose for B-frag loads)
__global__ void k_cvt_w(const float* __restrict__ W, unsigned short* __restrict__ WT) {
    int i = blockIdx.x * blockDim.x + threadIdx.x;
    if (i >= KDIM * DIM) return;
    int k = i >> 7, j = i & 127;
    WT[(size_t)j * KDIM + k] = f2bf(W[i]);
}

// ---------------------------------------------------------------------------
// 8) Fused SpMM v3: wave = one NODE, 16-lane group = one RELATION.
//    Each group owns the full 256B row for its relation: walks its ~16-edge
//    CSR row with 8-deep gather batches (32 gathers in flight per wave),
//    binary tail (4/2/1), no cross-group reduction, no idle lanes on store.
//    pk reads per batch = 8 consecutive int2 = one 64B line per group.
// ---------------------------------------------------------------------------
#define FMA8(u, cc) do { \
    acc0 += (cc) * __uint_as_float((unsigned)(u).x << 16); \
    acc1 += (cc) * __uint_as_float((unsigned)(u).x & 0xffff0000u); \
    acc2 += (cc) * __uint_as_float((unsigned)(u).y << 16); \
    acc3 += (cc) * __uint_as_float((unsigned)(u).y & 0xffff0000u); \
    acc4 += (cc) * __uint_as_float((unsigned)(u).z << 16); \
    acc5 += (cc) * __uint_as_float((unsigned)(u).z & 0xffff0000u); \
    acc6 += (cc) * __uint_as_float((unsigned)(u).w << 16); \
    acc7 += (cc) * __uint_as_float((unsigned)(u).w & 0xffff0000u); } while (0)

__global__ __launch_bounds__(256) void k_spmm4(const int* __restrict__ row_ptr,
                        const int2* __restrict__ pk_s,
                        const float* __restrict__ rinv_in, const int4* __restrict__ hb4,
                        int4* __restrict__ Tb4, int node0) {
    int wv   = threadIdx.x >> 6;          // wave = node sub-index (0..3)
    int lane = threadIdx.x & 63;
    int r    = lane >> 4;                 // 16-lane group = relation
    int m    = lane & 15;                 // owns features [8m, 8m+8)
    int nl   = blockIdx.x * 4 + wv;       // local row within half
    int node = node0 + nl;
    int k0 = row_ptr[r * (N_NODE + 1) + node];
    int k1 = row_ptr[r * (N_NODE + 1) + node + 1];
    const int2* pp = pk_s + (size_t)r * N_EDGE;
    float acc0 = 0.f, acc1 = 0.f, acc2 = 0.f, acc3 = 0.f;
    float acc4 = 0.f, acc5 = 0.f, acc6 = 0.f, acc7 = 0.f;
    int k = k0;
    for (; k + 7 < k1; k += 8) {          // 8 gathers in flight per group
        int2 p0 = pp[k],     p1 = pp[k + 1], p2 = pp[k + 2], p3 = pp[k + 3];
        int2 p4 = pp[k + 4], p5 = pp[k + 5], p6 = pp[k + 6], p7 = pp[k + 7];
        int4 u0 = hb4[(size_t)p0.x * 16 + m];
        int4 u1 = hb4[(size_t)p1.x * 16 + m];
        int4 u2 = hb4[(size_t)p2.x * 16 + m];
        int4 u3 = hb4[(size_t)p3.x * 16 + m];
        int4 u4 = hb4[(size_t)p4.x * 16 + m];
        int4 u5 = hb4[(size_t)p5.x * 16 + m];
        int4 u6 = hb4[(size_t)p6.x * 16 + m];
        int4 u7 = hb4[(size_t)p7.x * 16 + m];
        FMA8(u0, __int_as_float(p0.y));
        FMA8(u1, __int_as_float(p1.y));
        FMA8(u2, __int_as_float(p2.y));
        FMA8(u3, __int_as_float(p3.y));
        FMA8(u4, __int_as_float(p4.y));
        FMA8(u5, __int_as_float(p5.y));
        FMA8(u6, __int_as_float(p6.y));
        FMA8(u7, __int_as_float(p7.y));
    }
    if (k + 3 < k1) {                     // 4-wide tail step
        int2 p0 = pp[k], p1 = pp[k + 1], p2 = pp[k + 2], p3 = pp[k + 3];
        int4 u0 = hb4[(size_t)p0.x * 16 + m];
        int4 u1 = hb4[(size_t)p1.x * 16 + m];
        int4 u2 = hb4[(size_t)p2.x * 16 + m];
        int4 u3 = hb4[(size_t)p3.x * 16 + m];
        FMA8(u0, __int_as_float(p0.y));
        FMA8(u1, __int_as_float(p1.y));
        FMA8(u2, __int_as_float(p2.y));
        FMA8(u3, __int_as_float(p3.y));
        k += 4;
    }
    if (k + 1 < k1) {                     // 2-wide tail step
        int2 p0 = pp[k], p1 = pp[k + 1];
        int4 u0 = hb4[(size_t)p0.x * 16 + m];
        int4 u1 = hb4[(size_t)p1.x * 16 + m];
        FMA8(u0, __int_as_float(p0.y));
        FMA8(u1, __int_as_float(p1.y));
        k += 2;
    }
    if (k < k1) {
        int2 p0 = pp[k];
        int4 u0 = hb4[(size_t)p0.x * 16 + m];
        FMA8(u0, __int_as_float(p0.y));
    }
    float ri = rinv_in[r * N_NODE + node];
    int4 o;
    o.x = (int)(((unsigned)f2bf(acc1 * ri) << 16) | (unsigned)f2bf(acc0 * ri));
    o.y = (int)(((unsigned)f2bf(acc3 * ri) << 16) | (unsigned)f2bf(acc2 * ri));
    o.z = (int)(((unsigned)f2bf(acc5 * ri) << 16) | (unsigned)f2bf(acc4 * ri));
    o.w = (int)(((unsigned)f2bf(acc7 * ri) << 16) | (unsigned)f2bf(acc6 * ri));
    Tb4[(size_t)nl * 64 + r * 16 + m] = o;       // same 512-bf16 row layout
}

// ---------------------------------------------------------------------------
// 9) MFMA GEMM: out[HALF_N,128] = relu(T[HALF_N,512] @ Wcat[512,128] + bias_sum)
//    mfma_f32_16x16x32_bf16; verified frag layouts (A: m=lane&15,k=(lane>>4)*8+j;
//    C/D: col=lane&15, row=(lane>>4)*4+reg). WT (128KB) L2-resident, no LDS.
// ---------------------------------------------------------------------------
__global__ __launch_bounds__(256) void k_gemm(const unsigned short* __restrict__ Tb,
                                              const unsigned short* __restrict__ WT,
                                              const float* __restrict__ b,
                                              float* __restrict__ outf,
                                              unsigned short* __restrict__ outb,
                                              int node0) {
    int lane = threadIdx.x & 63;
    int wv   = threadIdx.x >> 6;
    int row0 = blockIdx.x * 64 + wv * 16;
    if (row0 >= HALF_N) return;            // HALF_N % 16 == 0: full-or-empty
    int m  = lane & 15;
    int kg = lane >> 4;

    f32x4 acc[8];
#pragma unroll
    for (int t = 0; t < 8; ++t) acc[t] = (f32x4){0.f, 0.f, 0.f, 0.f};

    const unsigned short* arow = Tb + (size_t)(row0 + m) * KDIM + kg * 8;
    for (int k0 = 0; k0 < KDIM; k0 += 32) {
        bf16x8 af = *(const bf16x8*)(arow + k0);
#pragma unroll
        for (int t = 0; t < 8; ++t) {
            bf16x8 bf = *(const bf16x8*)(WT + (size_t)(t * 16 + m) * KDIM + k0 + kg * 8);
            acc[t] = __builtin_amdgcn_mfma_f32_16x16x32_bf16(af, bf, acc[t], 0, 0, 0);
        }
    }

    int rbase = row0 + kg * 4;
#pragma unroll
    for (int t = 0; t < 8; ++t) {
        int col = t * 16 + m;
        float bs = b[col] + b[DIM + col] + b[2 * DIM + col] + b[3 * DIM + col];
#pragma unroll
        for (int rg = 0; rg < 4; ++rg) {
            float v = acc[t][rg] + bs;
            v = v > 0.f ? v : 0.f;         // relu in BOTH layers per reference
            size_t o = (size_t)(node0 + rbase + rg) * DIM + col;
            if (outb) outb[o] = f2bf(v);
            else      outf[o] = v;
        }
    }
}

// ---------------------------------------------------------------------------
extern "C" void kernel_launch(void* const* d_in, const int* in_sizes, int n_in,
                              void* d_out, int out_size, void* d_ws, size_t ws_size,
                              hipStream_t stream) {
    const float* x   = (const float*)d_in[0];
    const int*   src = (const int*)  d_in[1];
    const int*   dst = (const int*)  d_in[2];
    const float* ew  = (const float*)d_in[3];
    const float* W1  = (const float*)d_in[4];
    const float* b1  = (const float*)d_in[5];
    const float* W2  = (const float*)d_in[6];
    const float* b2  = (const float*)d_in[7];
    float* out = (float*)d_out;

    // Workspace carve-up (~162 MB, same proven footprint).
    char* p = (char*)d_ws;
    auto alloc = [&](size_t bytes) -> char* {
        char* q = p;
        p += (bytes + 255) & ~(size_t)255;
        return q;
    };
    const size_t RN = (size_t)N_REL * N_NODE;
    int*   cnt_in     = (int*)  alloc(RN * 4);
    float* rinv_out   = (float*)alloc(RN * 4);
    float* rinv_in    = (float*)alloc(RN * 4);
    int*   row_ptr    = (int*)  alloc((size_t)N_REL * (N_NODE + 1) * 4);
    int*   partials   = (int*)  alloc(N_REL * NCH * 4);
    int*   chunk_base = (int*)  alloc(N_REL * NCH * 4);
    unsigned short* WT1b = (unsigned short*)alloc((size_t)KDIM * DIM * 2);  // 128KB
    unsigned short* WT2b = (unsigned short*)alloc((size_t)KDIM * DIM * 2);  // 128KB
    int2*  pk_s       = (int2*) alloc((size_t)N_REL * N_EDGE * 8);          // 51.2 MB
    char*  Treg       =         alloc((size_t)HALF_N * KDIM * 2);           // 51.2 MB
    char*  hreg       =         alloc((size_t)N_REL * NCHUNK * N_NODE * 4); // 51.2 MB

    // Aliases:
    // Pd (dst partials -> CSR bases) in Treg: dead after k_scatter5, before spmm.
    // Ps (src partials) in hreg: dead after k_reduce_rinv; then hreg splits:
    //   [0, 25.6MB)   h_mid_b : bf16 layer-1 output
    //   [25.6, 51.2)  xb      : bf16 copy of x
    int* Pd = (int*)Treg;
    int* Ps = (int*)hreg;
    unsigned short* h_mid_b = (unsigned short*)hreg;
    unsigned short* xb      = (unsigned short*)(hreg + (size_t)N_NODE * DIM * 2);
    unsigned short* Tb      = (unsigned short*)Treg;

    dim3 gridH(NCHUNK, NTILE, N_REL);   // 32 x 4 x 4 = 512 blocks of 512 thr
    k_hist<<<gridH, 512, 0, stream>>>(dst, Pd);
    k_hist<<<gridH, 512, 0, stream>>>(src, Ps);
    k_reduce_rinv<<<((int)RN + 255) / 256, 256, 0, stream>>>(Pd, Ps, cnt_in, rinv_in, rinv_out);
    k_cvt<<<(N_NODE * DIM / 4 + 255) / 256, 256, 0, stream>>>(x, xb);  // Ps dead
    k_cvt_w<<<(KDIM * DIM + 255) / 256, 256, 0, stream>>>(W1, WT1b);
    k_cvt_w<<<(KDIM * DIM + 255) / 256, 256, 0, stream>>>(W2, WT2b);
    k_chunk_sum<<<dim3(NCH, N_REL), 256, 0, stream>>>(cnt_in, partials);
    k_scan_partials<<<1, 256, 0, stream>>>(partials, chunk_base, row_ptr);
    k_chunk_scan<<<dim3(NCH, N_REL), 256, 0, stream>>>(cnt_in, chunk_base, row_ptr);
    k_base<<<((int)RN + 255) / 256, 256, 0, stream>>>(Pd, row_ptr);
    k_scatter5<<<gridH, 512, 0, stream>>>(src, dst, ew, Pd, rinv_out, pk_s);

    const int spmm_grid = HALF_N / 4;          // 12500 blocks: 4 nodes x 4 rel-groups
    const int gemm_grid = (HALF_N + 63) / 64;  // 782

    // layer 1: xb (bf16) -> h_mid_b (bf16), two halves through Tb
    for (int h = 0; h < 2; ++h) {
        k_spmm4<<<spmm_grid, 256, 0, stream>>>(row_ptr, pk_s, rinv_in,
                                               (const int4*)xb, (int4*)Tb, h * HALF_N);
        k_gemm<<<gemm_grid, 256, 0, stream>>>(Tb, WT1b, b1, (float*)nullptr, h_mid_b, h * HALF_N);
    }
    // layer 2: h_mid_b (bf16) -> out (fp32)
    for (int h = 0; h < 2; ++h) {
        k_spmm4<<<spmm_grid, 256, 0, stream>>>(row_ptr, pk_s, rinv_in,
                                               (const int4*)h_mid_b, (int4*)Tb, h * HALF_N);
        k_gemm<<<gemm_grid, 256, 0, stream>>>(Tb, WT2b, b2, out, (unsigned short*)nullptr, h * HALF_N);
    }
}

// Round 5
// 1135.560 us; speedup vs baseline: 1.7312x; 1.0765x over previous
//
#include <hip/hip_runtime.h>
#include <hip/hip_bf16.h>
#include <cstdint>
#include <cstddef>

// Problem constants
#define N_NODE 100000
#define N_EDGE 1600000
#define N_REL  4
#define DIM    128
#define KDIM   512                               // N_REL * DIM stacked
#define CHUNK  2048
#define NCH    ((N_NODE + CHUNK - 1) / CHUNK)   // 49

// Histogram/scatter tiling: packed u16 counters -> TS=25000 in 50KB LDS,
// 4 passes. 512-thread blocks; grid 512 = 2 blocks/CU (grid-capped).
// (Global-atomic variant is 2x WORSE: cross-XCD RMW = 400MB HBM write.
//  Phase-grouped prefetch variant: FETCH -90MB but +9us -> NOT BW-bound.)
#define CH_E   50000                             // edges per chunk (div by 8)
#define NCHUNK 32                                // chunks (Pd table caps this)
#define TS     25000                             // node-tile size (even)
#define NTILE  4                                 // ceil(100000/25000)

typedef __attribute__((ext_vector_type(8))) short bf16x8;   // 8 bf16 (4 VGPRs)
typedef __attribute__((ext_vector_type(4))) float f32x4;    // 4 fp32 acc

__device__ inline unsigned short f2bf(float f) {
    __hip_bfloat16 b = __float2bfloat16(f);
    return *reinterpret_cast<unsigned short*>(&b);
}

// ---------------------------------------------------------------------------
// 1) Tiled LDS histogram, packed u16 fields (count <= 50000 < 2^16).
//    8 edges per thread-iteration for deeper load pipelining.
// ---------------------------------------------------------------------------
__global__ __launch_bounds__(512) void k_hist(const int* __restrict__ idx,
                                              int* __restrict__ P) {
    __shared__ unsigned hist[TS / 2];            // 50 KB
    int c = blockIdx.x, t = blockIdx.y, r = blockIdx.z;
    for (int i = threadIdx.x; i < TS / 2; i += 512) hist[i] = 0;
    __syncthreads();
    int n0 = t * TS;
    const int4* ip = (const int4*)(idx + (size_t)r * N_EDGE + c * CH_E);
    for (int q = threadIdx.x * 2; q < CH_E / 4; q += 1024) {
        int4 d0 = ip[q], d1 = ip[q + 1];
        int dd[8] = {d0.x, d0.y, d0.z, d0.w, d1.x, d1.y, d1.z, d1.w};
#pragma unroll
        for (int i = 0; i < 8; ++i) {
            unsigned a = (unsigned)(dd[i] - n0);
            if (a < TS) atomicAdd(&hist[a >> 1], 1u << (16 * (a & 1)));
        }
    }
    __syncthreads();
    int* Pp = P + ((size_t)r * NCHUNK + c) * N_NODE;
    for (int i = threadIdx.x; i < TS; i += 512) {
        int n = n0 + i;
        if (n < N_NODE)
            Pp[n] = (int)((hist[i >> 1] >> (16 * (i & 1))) & 0xffffu);
    }
}

// 2) Reduce partials over chunks -> cnt_in (for scan) + rinv_in/out
__global__ void k_reduce_rinv(const int* __restrict__ Pd, const int* __restrict__ Ps,
                              int* __restrict__ cnt_in, float* __restrict__ rinv_in,
                              float* __restrict__ rinv_out) {
    int i = blockIdx.x * blockDim.x + threadIdx.x;   // r*N + n
    if (i >= N_REL * N_NODE) return;
    int r = i / N_NODE, n = i - r * N_NODE;
    int ci = 0, co = 0;
#pragma unroll
    for (int c = 0; c < NCHUNK; ++c) {
        ci += Pd[((size_t)r * NCHUNK + c) * N_NODE + n];
        co += Ps[((size_t)r * NCHUNK + c) * N_NODE + n];
    }
    cnt_in[i]   = ci;
    rinv_in[i]  = rsqrtf((float)max(ci, 1));
    rinv_out[i] = rsqrtf((float)max(co, 1));
}

// ---------------------------------------------------------------------------
// 3) CSR-by-dst row_ptr: chunk sums -> scan partials -> chunk scan
// ---------------------------------------------------------------------------
__global__ void k_chunk_sum(const int* __restrict__ cnt_in, int* __restrict__ partials) {
    int r = blockIdx.y, ch = blockIdx.x;
    __shared__ int sdata[256];
    int s = 0;
    for (int i = 0; i < CHUNK / 256; ++i) {
        int n = ch * CHUNK + i * 256 + threadIdx.x;
        if (n < N_NODE) s += cnt_in[r * N_NODE + n];
    }
    sdata[threadIdx.x] = s;
    __syncthreads();
    for (int off = 128; off > 0; off >>= 1) {
        if (threadIdx.x < off) sdata[threadIdx.x] += sdata[threadIdx.x + off];
        __syncthreads();
    }
    if (threadIdx.x == 0) partials[r * NCH + ch] = sdata[0];
}

__global__ void k_scan_partials(const int* __restrict__ partials,
                                int* __restrict__ chunk_base, int* __restrict__ row_ptr) {
    __shared__ int sp[N_REL * NCH];
    int t = threadIdx.x;
    if (t < N_REL * NCH) sp[t] = partials[t];
    __syncthreads();
    if (t == 0) {
        for (int r = 0; r < N_REL; ++r) {
            int run = 0;
            for (int ch = 0; ch < NCH; ++ch) {
                chunk_base[r * NCH + ch] = run;
                run += sp[r * NCH + ch];
            }
            row_ptr[r * (N_NODE + 1) + N_NODE] = N_EDGE;
        }
    }
}

__global__ void k_chunk_scan(const int* __restrict__ cnt_in,
                             const int* __restrict__ chunk_base, int* __restrict__ row_ptr) {
    int r = blockIdx.y, ch = blockIdx.x;
    __shared__ int tsum[256];
    int base_n = ch * CHUNK;
    int vals[8];
    int loc = 0;
    for (int i = 0; i < 8; ++i) {
        int n = base_n + threadIdx.x * 8 + i;
        vals[i] = (n < N_NODE) ? cnt_in[r * N_NODE + n] : 0;
        loc += vals[i];
    }
    tsum[threadIdx.x] = loc;
    __syncthreads();
    for (int off = 1; off < 256; off <<= 1) {     // Hillis-Steele inclusive scan
        int y = (threadIdx.x >= off) ? tsum[threadIdx.x - off] : 0;
        __syncthreads();
        tsum[threadIdx.x] += y;
        __syncthreads();
    }
    int pos = chunk_base[r * NCH + ch] + tsum[threadIdx.x] - loc;  // exclusive
    for (int i = 0; i < 8; ++i) {
        int n = base_n + threadIdx.x * 8 + i;
        if (n < N_NODE) { row_ptr[r * (N_NODE + 1) + n] = pos; pos += vals[i]; }
    }
}

// 4) In-place: P[r][c][n] := row_ptr[r][n] + sum_{c'<c} P[r][c'][n]
__global__ void k_base(int* __restrict__ P, const int* __restrict__ row_ptr) {
    int i = blockIdx.x * blockDim.x + threadIdx.x;
    if (i >= N_REL * N_NODE) return;
    int r = i / N_NODE, n = i - r * N_NODE;
    int run = row_ptr[r * (N_NODE + 1) + n];
#pragma unroll
    for (int c = 0; c < NCHUNK; ++c) {
        size_t o = ((size_t)r * NCHUNK + c) * N_NODE + n;
        int p = P[o];
        P[o] = run;
        run += p;
    }
}

// 5) Scatter: packed u16 LOCAL cursors (init 0), CSR base added per-hit via
//    L2-resident 64KB-window gather; rinv_out folded in. (Proven 265us form.)
__global__ __launch_bounds__(512) void k_scatter5(const int* __restrict__ src,
                          const int* __restrict__ dst, const float* __restrict__ ew,
                          const int* __restrict__ base, const float* __restrict__ rinv_out,
                          int2* __restrict__ pk_s) {
    __shared__ unsigned cur[TS / 2];             // 50 KB, local ranks
    int c = blockIdx.x, t = blockIdx.y, r = blockIdx.z;
    for (int i = threadIdx.x; i < TS / 2; i += 512) cur[i] = 0;
    __syncthreads();
    int n0 = t * TS;
    int e0 = c * CH_E;
    const int*   bp = base + ((size_t)r * NCHUNK + c) * N_NODE + n0;
    const float* ro = rinv_out + (size_t)r * N_NODE;
    size_t roff = (size_t)r * N_EDGE;
    for (int e = e0 + threadIdx.x * 4; e < e0 + CH_E; e += 2048) {
        int4   d4 = *(const int4*)  (dst + roff + e);
        int4   s4 = *(const int4*)  (src + roff + e);
        float4 w4 = *(const float4*)(ew  + roff + e);
        unsigned a; unsigned old; int rank;
        a = (unsigned)(d4.x - n0);
        if (a < TS) {
            old = atomicAdd(&cur[a >> 1], 1u << (16 * (a & 1)));
            rank = (int)((old >> (16 * (a & 1))) & 0xffffu);
            pk_s[roff + bp[a] + rank] = make_int2(s4.x, __float_as_int(w4.x * ro[s4.x]));
        }
        a = (unsigned)(d4.y - n0);
        if (a < TS) {
            old = atomicAdd(&cur[a >> 1], 1u << (16 * (a & 1)));
            rank = (int)((old >> (16 * (a & 1))) & 0xffffu);
            pk_s[roff + bp[a] + rank] = make_int2(s4.y, __float_as_int(w4.y * ro[s4.y]));
        }
        a = (unsigned)(d4.z - n0);
        if (a < TS) {
            old = atomicAdd(&cur[a >> 1], 1u << (16 * (a & 1)));
            rank = (int)((old >> (16 * (a & 1))) & 0xffffu);
            pk_s[roff + bp[a] + rank] = make_int2(s4.z, __float_as_int(w4.z * ro[s4.z]));
        }
        a = (unsigned)(d4.w - n0);
        if (a < TS) {
            old = atomicAdd(&cur[a >> 1], 1u << (16 * (a & 1)));
            rank = (int)((old >> (16 * (a & 1))) & 0xffffu);
            pk_s[roff + bp[a] + rank] = make_int2(s4.w, __float_as_int(w4.w * ro[s4.w]));
        }
    }
}

// 7a) fp32 -> bf16 matrix convert (4 elems/thread)
__global__ void k_cvt(const float* __restrict__ x, unsigned short* __restrict__ xb) {
    int i = blockIdx.x * blockDim.x + threadIdx.x;
    if (i >= N_NODE * DIM / 4) return;
    float4 v = ((const float4*)x)[i];
    ushort4 o;
    o.x = f2bf(v.x); o.y = f2bf(v.y); o.z = f2bf(v.z); o.w = f2bf(v.w);
    ((ushort4*)xb)[i] = o;
}

// 7b) W [512][128] fp32 -> WT [128][512] bf16 (transpose for B-frag loads)
__global__ void k_cvt_w(const float* __restrict__ W, unsigned short* __restrict__ WT) {
    int i = blockIdx.x * blockDim.x + threadIdx.x;
    if (i >= KDIM * DIM) return;
    int k = i >> 7, j = i & 127;
    WT[(size_t)j * KDIM + k] = f2bf(W[i]);
}

// ---------------------------------------------------------------------------
// 8) FUSED SpMM + MFMA GEMM. Block = 512 threads, 64 nodes, 64KB LDS A-tile.
//    Phase 1 (gather): 32 x 16-lane groups; group owns one (node, rel) CSR
//    row at a time (8 tasks each), 8-deep gather batches, result written as
//    bf16 to swizzled LDS (byte ^= (row&7)<<4 kills the 1024B-stride bank
//    conflict on phase-2 ds_read_b128).
//    Phase 2 (GEMM): 8 waves = 4 row-tiles x 2 col-halves; A-frags from LDS,
//    B from L2-resident WT[128][512]; verified mfma_f32_16x16x32_bf16 layout
//    (A: m=lane&15, k=(lane>>4)*8+j; C/D: col=lane&15, row=(lane>>4)*4+reg).
//    Eliminates the Tb roundtrip (204MB) and the standalone gemm dispatches.
// ---------------------------------------------------------------------------
#define FMA8(u, cc) do { \
    acc0 += (cc) * __uint_as_float((unsigned)(u).x << 16); \
    acc1 += (cc) * __uint_as_float((unsigned)(u).x & 0xffff0000u); \
    acc2 += (cc) * __uint_as_float((unsigned)(u).y << 16); \
    acc3 += (cc) * __uint_as_float((unsigned)(u).y & 0xffff0000u); \
    acc4 += (cc) * __uint_as_float((unsigned)(u).z << 16); \
    acc5 += (cc) * __uint_as_float((unsigned)(u).z & 0xffff0000u); \
    acc6 += (cc) * __uint_as_float((unsigned)(u).w << 16); \
    acc7 += (cc) * __uint_as_float((unsigned)(u).w & 0xffff0000u); } while (0)

__global__ __launch_bounds__(512, 4) void k_fused(const int* __restrict__ row_ptr,
                        const int2* __restrict__ pk_s,
                        const float* __restrict__ rinv_in, const int4* __restrict__ hb4,
                        const unsigned short* __restrict__ WT,
                        const float* __restrict__ b,
                        float* __restrict__ outf, unsigned short* __restrict__ outb) {
    __shared__ unsigned short Als[64 * KDIM];    // 64KB -> 2 blocks/CU
    int node_base = blockIdx.x * 64;
    int limit = N_NODE - node_base;              // >=1; last block has 32
    int lane = threadIdx.x & 63;
    int m = lane & 15;

    // ---- Phase 1: gather-spmm into LDS ----
    {
        int g = threadIdx.x >> 4;                // 32 groups of 16 lanes
        for (int i = 0; i < 8; ++i) {
            int tt = g + 32 * i;                 // 0..255 = 64 nodes x 4 rel
            int nl = tt >> 2, r = tt & 3;
            unsigned lds_off = (unsigned)nl * (KDIM * 2)
                             + (((unsigned)(r * 256 + m * 16)) ^ (((unsigned)nl & 7u) << 4));
            if (nl >= limit) {                   // pad rows: zero (stores guarded too)
                *(int4*)((char*)Als + lds_off) = make_int4(0, 0, 0, 0);
                continue;
            }
            int node = node_base + nl;
            int k0 = row_ptr[r * (N_NODE + 1) + node];
            int k1 = row_ptr[r * (N_NODE + 1) + node + 1];
            const int2* pp = pk_s + (size_t)r * N_EDGE;
            float acc0 = 0.f, acc1 = 0.f, acc2 = 0.f, acc3 = 0.f;
            float acc4 = 0.f, acc5 = 0.f, acc6 = 0.f, acc7 = 0.f;
            int k = k0;
            for (; k + 7 < k1; k += 8) {          // 8 gathers in flight per lane
                int2 p0 = pp[k],     p1 = pp[k + 1], p2 = pp[k + 2], p3 = pp[k + 3];
                int2 p4 = pp[k + 4], p5 = pp[k + 5], p6 = pp[k + 6], p7 = pp[k + 7];
                int4 u0 = hb4[(size_t)p0.x * 16 + m];
                int4 u1 = hb4[(size_t)p1.x * 16 + m];
                int4 u2 = hb4[(size_t)p2.x * 16 + m];
                int4 u3 = hb4[(size_t)p3.x * 16 + m];
                int4 u4 = hb4[(size_t)p4.x * 16 + m];
                int4 u5 = hb4[(size_t)p5.x * 16 + m];
                int4 u6 = hb4[(size_t)p6.x * 16 + m];
                int4 u7 = hb4[(size_t)p7.x * 16 + m];
                FMA8(u0, __int_as_float(p0.y));
                FMA8(u1, __int_as_float(p1.y));
                FMA8(u2, __int_as_float(p2.y));
                FMA8(u3, __int_as_float(p3.y));
                FMA8(u4, __int_as_float(p4.y));
                FMA8(u5, __int_as_float(p5.y));
                FMA8(u6, __int_as_float(p6.y));
                FMA8(u7, __int_as_float(p7.y));
            }
            if (k + 3 < k1) {                     // 4-wide tail
                int2 p0 = pp[k], p1 = pp[k + 1], p2 = pp[k + 2], p3 = pp[k + 3];
                int4 u0 = hb4[(size_t)p0.x * 16 + m];
                int4 u1 = hb4[(size_t)p1.x * 16 + m];
                int4 u2 = hb4[(size_t)p2.x * 16 + m];
                int4 u3 = hb4[(size_t)p3.x * 16 + m];
                FMA8(u0, __int_as_float(p0.y));
                FMA8(u1, __int_as_float(p1.y));
                FMA8(u2, __int_as_float(p2.y));
                FMA8(u3, __int_as_float(p3.y));
                k += 4;
            }
            if (k + 1 < k1) {                     // 2-wide tail
                int2 p0 = pp[k], p1 = pp[k + 1];
                int4 u0 = hb4[(size_t)p0.x * 16 + m];
                int4 u1 = hb4[(size_t)p1.x * 16 + m];
                FMA8(u0, __int_as_float(p0.y));
                FMA8(u1, __int_as_float(p1.y));
                k += 2;
            }
            if (k < k1) {
                int2 p0 = pp[k];
                int4 u0 = hb4[(size_t)p0.x * 16 + m];
                FMA8(u0, __int_as_float(p0.y));
            }
            float ri = rinv_in[r * N_NODE + node];
            int4 o;
            o.x = (int)(((unsigned)f2bf(acc1 * ri) << 16) | (unsigned)f2bf(acc0 * ri));
            o.y = (int)(((unsigned)f2bf(acc3 * ri) << 16) | (unsigned)f2bf(acc2 * ri));
            o.z = (int)(((unsigned)f2bf(acc5 * ri) << 16) | (unsigned)f2bf(acc4 * ri));
            o.w = (int)(((unsigned)f2bf(acc7 * ri) << 16) | (unsigned)f2bf(acc6 * ri));
            *(int4*)((char*)Als + lds_off) = o;
        }
    }
    __syncthreads();

    // ---- Phase 2: MFMA GEMM from LDS ----
    int wv   = threadIdx.x >> 6;          // 8 waves
    int row0 = (wv >> 1) * 16;            // 4 row-tiles of 16
    int col0 = (wv & 1) * 64;             // 2 col-halves of 64
    int kg   = lane >> 4;

    f32x4 acc[4];
#pragma unroll
    for (int t = 0; t < 4; ++t) acc[t] = (f32x4){0.f, 0.f, 0.f, 0.f};

    int arow = row0 + m;
    unsigned abase = (unsigned)arow * (KDIM * 2);
    unsigned axor  = ((unsigned)arow & 7u) << 4;
    for (int k0 = 0; k0 < KDIM; k0 += 32) {
        unsigned aoff = abase + ((((unsigned)(k0 + kg * 8)) * 2u) ^ axor);
        bf16x8 af = *(const bf16x8*)((const char*)Als + aoff);
#pragma unroll
        for (int t = 0; t < 4; ++t) {
            int col = col0 + t * 16 + m;
            bf16x8 bf = *(const bf16x8*)(WT + (size_t)col * KDIM + k0 + kg * 8);
            acc[t] = __builtin_amdgcn_mfma_f32_16x16x32_bf16(af, bf, acc[t], 0, 0, 0);
        }
    }

#pragma unroll
    for (int t = 0; t < 4; ++t) {
        int col = col0 + t * 16 + m;
        float bs = b[col] + b[DIM + col] + b[2 * DIM + col] + b[3 * DIM + col];
#pragma unroll
        for (int rg = 0; rg < 4; ++rg) {
            int row = row0 + kg * 4 + rg;
            int node = node_base + row;
            if (node < N_NODE) {
                float v = acc[t][rg] + bs;
                v = v > 0.f ? v : 0.f;     // relu in BOTH layers per reference
                size_t o = (size_t)node * DIM + col;
                if (outb) outb[o] = f2bf(v);
                else      outf[o] = v;
            }
        }
    }
}

// ---------------------------------------------------------------------------
extern "C" void kernel_launch(void* const* d_in, const int* in_sizes, int n_in,
                              void* d_out, int out_size, void* d_ws, size_t ws_size,
                              hipStream_t stream) {
    const float* x   = (const float*)d_in[0];
    const int*   src = (const int*)  d_in[1];
    const int*   dst = (const int*)  d_in[2];
    const float* ew  = (const float*)d_in[3];
    const float* W1  = (const float*)d_in[4];
    const float* b1  = (const float*)d_in[5];
    const float* W2  = (const float*)d_in[6];
    const float* b2  = (const float*)d_in[7];
    float* out = (float*)d_out;

    // Workspace carve-up (~162 MB, same proven footprint).
    char* p = (char*)d_ws;
    auto alloc = [&](size_t bytes) -> char* {
        char* q = p;
        p += (bytes + 255) & ~(size_t)255;
        return q;
    };
    const size_t RN = (size_t)N_REL * N_NODE;
    int*   cnt_in     = (int*)  alloc(RN * 4);
    float* rinv_out   = (float*)alloc(RN * 4);
    float* rinv_in    = (float*)alloc(RN * 4);
    int*   row_ptr    = (int*)  alloc((size_t)N_REL * (N_NODE + 1) * 4);
    int*   partials   = (int*)  alloc(N_REL * NCH * 4);
    int*   chunk_base = (int*)  alloc(N_REL * NCH * 4);
    unsigned short* WT1b = (unsigned short*)alloc((size_t)KDIM * DIM * 2);  // 128KB
    unsigned short* WT2b = (unsigned short*)alloc((size_t)KDIM * DIM * 2);  // 128KB
    int2*  pk_s       = (int2*) alloc((size_t)N_REL * N_EDGE * 8);          // 51.2 MB
    char*  Treg       =         alloc((size_t)N_REL * NCHUNK * N_NODE * 4); // 51.2 MB
    char*  hreg       =         alloc((size_t)N_REL * NCHUNK * N_NODE * 4); // 51.2 MB

    // Aliases:
    // Pd (dst partials -> CSR bases) in Treg: dead after k_scatter5.
    // Ps (src partials) in hreg: dead after k_reduce_rinv; then hreg splits:
    //   [0, 25.6MB)   h_mid_b : bf16 layer-1 output
    //   [25.6, 51.2)  xb      : bf16 copy of x
    int* Pd = (int*)Treg;
    int* Ps = (int*)hreg;
    unsigned short* h_mid_b = (unsigned short*)hreg;
    unsigned short* xb      = (unsigned short*)(hreg + (size_t)N_NODE * DIM * 2);

    dim3 gridH(NCHUNK, NTILE, N_REL);   // 32 x 4 x 4 = 512 blocks of 512 thr
    k_hist<<<gridH, 512, 0, stream>>>(dst, Pd);
    k_hist<<<gridH, 512, 0, stream>>>(src, Ps);
    k_reduce_rinv<<<((int)RN + 255) / 256, 256, 0, stream>>>(Pd, Ps, cnt_in, rinv_in, rinv_out);
    k_cvt<<<(N_NODE * DIM / 4 + 255) / 256, 256, 0, stream>>>(x, xb);  // Ps dead
    k_cvt_w<<<(KDIM * DIM + 255) / 256, 256, 0, stream>>>(W1, WT1b);
    k_cvt_w<<<(KDIM * DIM + 255) / 256, 256, 0, stream>>>(W2, WT2b);
    k_chunk_sum<<<dim3(NCH, N_REL), 256, 0, stream>>>(cnt_in, partials);
    k_scan_partials<<<1, 256, 0, stream>>>(partials, chunk_base, row_ptr);
    k_chunk_scan<<<dim3(NCH, N_REL), 256, 0, stream>>>(cnt_in, chunk_base, row_ptr);
    k_base<<<((int)RN + 255) / 256, 256, 0, stream>>>(Pd, row_ptr);
    k_scatter5<<<gridH, 512, 0, stream>>>(src, dst, ew, Pd, rinv_out, pk_s);

    const int fused_grid = (N_NODE + 63) / 64;   // 1563 blocks, 64 nodes each

    // layer 1: xb (bf16) -> h_mid_b (bf16)
    k_fused<<<fused_grid, 512, 0, stream>>>(row_ptr, pk_s, rinv_in,
                                            (const int4*)xb, WT1b, b1,
                                            (float*)nullptr, h_mid_b);
    // layer 2: h_mid_b (bf16) -> out (fp32)
    k_fused<<<fused_grid, 512, 0, stream>>>(row_ptr, pk_s, rinv_in,
                                            (const int4*)h_mid_b, WT2b, b2,
                                            out, (unsigned short*)nullptr);
}